// Round 9
// baseline (151.246 us; speedup 1.0000x reference)
//
#include <hip/hip_runtime.h>
#include <math.h>

#define DEV_INLINE __device__ __forceinline__

typedef short bf16x8 __attribute__((ext_vector_type(8)));
typedef float f32x4  __attribute__((ext_vector_type(4)));

// Problem constants: N=8, C=512, HW=1024, OC=3C=1536, G=8, gp=128

DEV_INLINE float bf2f(short h){
  union { unsigned u; float f; } x; x.u = ((unsigned)(unsigned short)h) << 16; return x.f;
}
DEV_INLINE short f2bf(float f){
  union { float f; unsigned u; } x; x.f = f;
  unsigned r = x.u + 0x7FFF + ((x.u >> 16) & 1);
  return (short)(r >> 16);
}

// ---------------- block reduction helpers (blockDim == 256) ----------------
template<bool MAXOP>
DEV_INLINE float block_reduce_f(float v){
  __shared__ float tmp[4];
  const int lane = threadIdx.x & 63, w = threadIdx.x >> 6;
  #pragma unroll
  for (int off = 32; off; off >>= 1){
    float o = __shfl_down(v, off);
    v = MAXOP ? fmaxf(v, o) : (v + o);
  }
  __syncthreads();
  if (lane == 0) tmp[w] = v;
  __syncthreads();
  return MAXOP ? fmaxf(fmaxf(tmp[0], tmp[1]), fmaxf(tmp[2], tmp[3]))
               : (tmp[0] + tmp[1] + tmp[2] + tmp[3]);
}

DEV_INLINE double block_reduce_d(double v){
  __shared__ double tmp[4];
  const int lane = threadIdx.x & 63, w = threadIdx.x >> 6;
  #pragma unroll
  for (int off = 32; off; off >>= 1) v += __shfl_down(v, off);
  __syncthreads();
  if (lane == 0) tmp[w] = v;
  __syncthreads();
  return tmp[0] + tmp[1] + tmp[2] + tmp[3];
}

// ---------------- MFMA tile machinery for gemm1 (single-buffer LDS; m99/m100:
// explicit dbuf doesn't help this structure) ----------------
DEV_INLINE void stage_tile(const short* __restrict__ g, int ldk, char* lds_region, int t){
  #pragma unroll
  for (int r = 0; r < 2; ++r){
    int o   = t * 16 + r * 4096;
    int row = o >> 6, wb = o & 63;
    int swb = wb ^ (((row >> 1) & 3) << 4);
    const short* src = g + (size_t)row * ldk + (swb >> 1);
    char* dst = lds_region + ((t >> 6) << 10) + (r << 12); // wave-uniform
    __builtin_amdgcn_global_load_lds((const __attribute__((address_space(1))) void*)src,
                                     (__attribute__((address_space(3))) void*)dst, 16, 0, 0);
  }
}

DEV_INLINE bf16x8 read_frag(const char* base, int row, int kgrp){
  int off = row * 64 + ((kgrp ^ ((row >> 1) & 3)) << 4);
  return *(const bf16x8*)(base + off);
}

template<int KTILES>
DEV_INLINE void mfma_loop(const short* __restrict__ A, int ldA,
                          const short* __restrict__ B, int ldB,
                          char* ldsA, char* ldsB, int t, f32x4 acc[4][4]){
  const int l = t & 63, w = t >> 6;
  const int wr = (w >> 1) * 64, wc = (w & 1) * 64;
  for (int kt = 0; kt < KTILES; ++kt){
    stage_tile(A + kt * 32, ldA, ldsA, t);
    stage_tile(B + kt * 32, ldB, ldsB, t);
    __syncthreads();
    bf16x8 af[4], bfr[4];
    #pragma unroll
    for (int m = 0; m < 4; ++m) af[m]  = read_frag(ldsA, wr + m * 16 + (l & 15), l >> 4);
    #pragma unroll
    for (int n = 0; n < 4; ++n) bfr[n] = read_frag(ldsB, wc + n * 16 + (l & 15), l >> 4);
    #pragma unroll
    for (int m = 0; m < 4; ++m)
      #pragma unroll
      for (int n = 0; n < 4; ++n)
        acc[m][n] = __builtin_amdgcn_mfma_f32_16x16x32_bf16(af[m], bfr[n], acc[m][n], 0, 0, 0);
    __syncthreads();
  }
}

// ---------------- K0: combined prep — Xt transpose-convert + W convert + zeroing ------
__global__ __launch_bounds__(256) void k_prep(const float* __restrict__ X, short* __restrict__ Xt,
                                              const float* __restrict__ W, short* __restrict__ Wbf,
                                              double* __restrict__ stats, float* __restrict__ S12){
  __shared__ short s[64][72];
  const int bid = blockIdx.x;
  const int t = threadIdx.x;
  if (bid < 1024){
    const int it = bid & 15, kt = (bid >> 4) & 7, b = bid >> 7;
    const int rl = t >> 2, cs = (t & 3) * 16;
    const float* src = X + ((size_t)b * 512 + kt * 64 + rl) * 1024 + it * 64 + cs;
    #pragma unroll
    for (int e = 0; e < 16; e += 4){
      float4 v = *(const float4*)(src + e);
      s[rl][cs + e + 0] = f2bf(v.x); s[rl][cs + e + 1] = f2bf(v.y);
      s[rl][cs + e + 2] = f2bf(v.z); s[rl][cs + e + 3] = f2bf(v.w);
    }
    __syncthreads();
    bf16x8 a0, a1;
    #pragma unroll
    for (int e = 0; e < 8; ++e){ a0[e] = s[cs + e][rl]; a1[e] = s[cs + 8 + e][rl]; }
    short* dst = Xt + ((size_t)b * 1024 + it * 64 + rl) * 512 + kt * 64 + cs;
    *(bf16x8*)dst = a0;
    *(bf16x8*)(dst + 8) = a1;
  } else {
    const int gi = (bid - 1024) * 256 + t;
    if (gi < 48) stats[gi] = 0.0;
    if (gi < 8192) S12[gi] = 0.f;
    const int i = gi * 4;
    float4 v = *(const float4*)(W + i);
    short4 o; o.x = f2bf(v.x); o.y = f2bf(v.y); o.z = f2bf(v.z); o.w = f2bf(v.w);
    *(short4*)(Wbf + i) = o;
  }
}

// V (per bg: Ybf rows [b*1536+g*192+128, +64) viewed [512][128]) -> Vt [bg][128][512]
__global__ __launch_bounds__(256) void k_vt(const short* __restrict__ Ybf, short* __restrict__ Vt){
  const int bg = blockIdx.z, iit = blockIdx.y, jt = blockIdx.x;
  const int b = bg >> 3, g = bg & 7;
  const short* V = Ybf + (size_t)(b * 1536 + g * 192 + 128) * 1024;
  __shared__ short s[64][72];
  const int t = threadIdx.x;
  const int rl = t >> 2, cs = (t & 3) * 16;
  const short* src = V + (size_t)(iit * 64 + rl) * 128 + jt * 64 + cs;
  *(bf16x8*)&s[rl][cs]     = *(const bf16x8*)src;
  *(bf16x8*)&s[rl][cs + 8] = *(const bf16x8*)(src + 8);
  __syncthreads();
  bf16x8 a0, a1;
  #pragma unroll
  for (int e = 0; e < 8; ++e){ a0[e] = s[cs + e][rl]; a1[e] = s[cs + 8 + e][rl]; }
  short* dst = Vt + ((size_t)bg * 128 + jt * 64 + rl) * 512 + iit * 64 + cs;
  *(bf16x8*)dst = a0;
  *(bf16x8*)(dst + 8) = a1;
}

// ---------------- K1: Ybf = bf16( W @ X ), pre-LN ----------------
__global__ __launch_bounds__(256) void k_gemm1(const short* __restrict__ Wbf,
                                               const short* __restrict__ Xt,
                                               short* __restrict__ Ybf){
  const int b = blockIdx.z, mt = blockIdx.y, nt = blockIdx.x;
  __shared__ char lds[16384];
  const int t = threadIdx.x;
  f32x4 acc[4][4];
  #pragma unroll
  for (int m = 0; m < 4; ++m)
    #pragma unroll
    for (int n = 0; n < 4; ++n) acc[m][n] = {0.f, 0.f, 0.f, 0.f};
  const short* A = Wbf + (size_t)mt * 128 * 512;
  const short* B = Xt + (size_t)b * 1024 * 512 + (size_t)nt * 128 * 512;
  mfma_loop<16>(A, 512, B, 512, lds, lds + 8192, t, acc);
  const int l = t & 63, w = t >> 6, wr = (w >> 1) * 64, wc = (w & 1) * 64;
  short* out = Ybf + (size_t)b * 1536 * 1024 + (size_t)(mt * 128 + wr) * 1024 + nt * 128 + wc;
  #pragma unroll
  for (int m = 0; m < 4; ++m)
    #pragma unroll
    for (int n = 0; n < 4; ++n)
      #pragma unroll
      for (int j = 0; j < 4; ++j)
        out[(size_t)(m * 16 + (l >> 4) * 4 + j) * 1024 + n * 16 + (l & 15)] = f2bf(acc[m][n][j]);
}

// ---------------- K1b: wave-per-row LN of Ybf (1024 cols) + q/k chunk sums ----------------
__global__ __launch_bounds__(256) void k_ln(short* __restrict__ Ybf,
                                            float* __restrict__ QS, float* __restrict__ KS){
  const int row = blockIdx.x * 4 + (threadIdx.x >> 6);   // b*1536 + o
  const int l = threadIdx.x & 63;
  short* p = Ybf + (size_t)row * 1024 + l * 16;
  bf16x8 v0 = *(const bf16x8*)p;
  bf16x8 v1 = *(const bf16x8*)(p + 8);
  float f[16];
  #pragma unroll
  for (int e = 0; e < 8; ++e){ f[e] = bf2f(v0[e]); f[8 + e] = bf2f(v1[e]); }
  float s1 = 0.f, s2 = 0.f;
  #pragma unroll
  for (int e = 0; e < 16; ++e){ s1 += f[e]; s2 += f[e] * f[e]; }
  #pragma unroll
  for (int off = 32; off; off >>= 1){ s1 += __shfl_xor(s1, off); s2 += __shfl_xor(s2, off); }
  float mean = s1 * (1.f / 1024.f);
  float r = rsqrtf(s2 * (1.f / 1024.f) - mean * mean + 1e-5f);
  float cs = 0.f;
  #pragma unroll
  for (int e = 0; e < 16; ++e){ f[e] = (f[e] - mean) * r; cs += f[e]; }
  bf16x8 o0, o1;
  #pragma unroll
  for (int e = 0; e < 8; ++e){ o0[e] = f2bf(f[e]); o1[e] = f2bf(f[8 + e]); }
  *(bf16x8*)p = o0;
  *(bf16x8*)(p + 8) = o1;
  // chunk sums: chunk = l>>3 (128 elems = 8 lanes x 16)
  cs += __shfl_xor(cs, 1); cs += __shfl_xor(cs, 2); cs += __shfl_xor(cs, 4);
  const int o = row % 1536, ol = o % 192;
  if ((l & 7) == 0 && ol < 128){
    const int b = row / 1536, g = o / 192;
    const int c = (ol & 63) * 8 + (l >> 3);
    const int idx = (b * 8 + g) * 512 + c;
    if (ol < 64) QS[idx] = cs; else KS[idx] = cs;
  }
}

// ---------------- K2: QKbf = bf16( q @ k^T ) + per-g sum/sumsq ----------------
// Reg-direct MFMA: K=128 fits in 4 chunks of 32; no LDS, no barriers in the K-loop.
// Fragment loads are 16 rows x 64B contiguous segments, all L2-resident.
__global__ __launch_bounds__(256) void k_qk(const short* __restrict__ Ybf,
                                            short* __restrict__ QKbf,
                                            double* __restrict__ stats){
  const int bg = blockIdx.z, mt = blockIdx.y, nt = blockIdx.x;
  const int b = bg >> 3, g = bg & 7;
  const int t = threadIdx.x, l = t & 63, w = t >> 6;
  const int wr = (w >> 1) * 64, wc = (w & 1) * 64;
  const short* __restrict__ q  = Ybf + (size_t)(b * 1536 + g * 192) * 1024 + (size_t)mt * 16384;
  const short* __restrict__ kp = Ybf + (size_t)(b * 1536 + g * 192) * 1024 + 65536 + (size_t)nt * 16384;
  f32x4 acc[4][4];
  #pragma unroll
  for (int m = 0; m < 4; ++m)
    #pragma unroll
    for (int n = 0; n < 4; ++n) acc[m][n] = {0.f, 0.f, 0.f, 0.f};
  const int rA = wr + (l & 15), rB = wc + (l & 15);
  const int co = (l >> 4) * 8;
  #pragma unroll 1
  for (int kk = 0; kk < 4; ++kk){
    bf16x8 af[4], bfr[4];
    #pragma unroll
    for (int m = 0; m < 4; ++m)
      af[m] = *(const bf16x8*)(q + (size_t)(rA + m * 16) * 128 + kk * 32 + co);
    #pragma unroll
    for (int n = 0; n < 4; ++n)
      bfr[n] = *(const bf16x8*)(kp + (size_t)(rB + n * 16) * 128 + kk * 32 + co);
    #pragma unroll
    for (int m = 0; m < 4; ++m)
      #pragma unroll
      for (int n = 0; n < 4; ++n)
        acc[m][n] = __builtin_amdgcn_mfma_f32_16x16x32_bf16(af[m], bfr[n], acc[m][n], 0, 0, 0);
  }
  short* out = QKbf + (size_t)bg * 262144 + (size_t)(mt * 128 + wr) * 512 + nt * 128 + wc;
  float s1 = 0.f, s2 = 0.f;
  #pragma unroll
  for (int m = 0; m < 4; ++m)
    #pragma unroll
    for (int n = 0; n < 4; ++n)
      #pragma unroll
      for (int j = 0; j < 4; ++j){
        float vl = acc[m][n][j];
        s1 += vl; s2 += vl * vl;
        out[(size_t)(m * 16 + (l >> 4) * 4 + j) * 512 + n * 16 + (l & 15)] = f2bf(vl);
      }
  float S1 = block_reduce_f<false>(s1);
  float S2 = block_reduce_f<false>(s2);
  if (t == 0){
    atomicAdd(&stats[g * 6 + 0], (double)S1);
    atomicAdd(&stats[g * 6 + 1], (double)S2);
  }
}

// ---------------- K3: qr/kr closed-form stats; 64 blocks (g x 8 c-chunks) ----------------
__global__ __launch_bounds__(256) void k_qrkr(const float* __restrict__ QS,
                                              const float* __restrict__ KS,
                                              const float* __restrict__ rel,
                                              double* __restrict__ stats){
  const int g = blockIdx.x & 7, ch = blockIdx.x >> 3;
  const int t = threadIdx.x;
  const int c = ch * 64 + (t >> 2), part = t & 3;
  float r1 = 0, r2 = 0, r3 = 0, r4 = 0;
  for (int d = part * 128; d < part * 128 + 128; ++d){
    float v0 = rel[c + d];        r1 += v0; r2 += v0 * v0;
    float v1 = rel[1023 + c + d]; r3 += v1; r4 += v1 * v1;
  }
  #pragma unroll
  for (int off = 1; off < 4; off <<= 1){
    r1 += __shfl_xor(r1, off); r2 += __shfl_xor(r2, off);
    r3 += __shfl_xor(r3, off); r4 += __shfl_xor(r4, off);
  }
  double sq1 = 0, sq2 = 0, sk1 = 0, sk2 = 0;
  if (part == 0){
    float qa = 0, qb = 0, ka = 0, kb = 0;
    for (int b = 0; b < 8; ++b){
      float v = QS[(size_t)(b * 8 + g) * 512 + c]; qa += v; qb += v * v;
      float w = KS[(size_t)(b * 8 + g) * 512 + c]; ka += w; kb += w * w;
    }
    sq1 = (double)r1 * qa; sq2 = (double)r2 * qb;
    sk1 = (double)r3 * ka; sk2 = (double)r4 * kb;
  }
  sq1 = block_reduce_d(sq1);
  sq2 = block_reduce_d(sq2);
  sk1 = block_reduce_d(sk1);
  sk2 = block_reduce_d(sk2);
  if (t == 0){
    atomicAdd(&stats[g * 6 + 2], sq1);
    atomicAdd(&stats[g * 6 + 3], sq2);
    atomicAdd(&stats[g * 6 + 4], sk1);
    atomicAdd(&stats[g * 6 + 5], sk2);
  }
}

// ---------------- fused BN + sum + softmax + sve; wave per row, no syncs ----------------
// No max subtraction: s is a sum of 3 BN-standardized fields (|s| ~ 20), exp fp32-safe.
// Validated numerically in R7 (identical absmax).
__global__ __launch_bounds__(256) void k_softmax(short* __restrict__ QKbf,
    const float* __restrict__ QS, const float* __restrict__ KS,
    const float* __restrict__ rel, const double* __restrict__ stats,
    const float* __restrict__ bnw, const float* __restrict__ bnb,
    const float* __restrict__ fqr, const float* __restrict__ fkr,
    const float* __restrict__ fsve, float* __restrict__ SVE, float* __restrict__ S12){
  const int row = blockIdx.x * 4 + (threadIdx.x >> 6);   // (b*8+g)*512 + c
  const int l = threadIdx.x & 63;
  const int bg = row >> 9, c = row & 511, g = bg & 7;
  // inline BN coefficients (uniform per block)
  const double M = 2097152.0; // 8*512*512
  double mu0  = stats[g*6+0] / M;
  double var0 = stats[g*6+1] / M - mu0*mu0;
  double A0d  = (double)bnw[g] / sqrt(var0 + 1e-5);
  double fq   = (double)fqr[0];
  double mu1  = fq * stats[g*6+2] / M;
  double var1 = fq*fq * stats[g*6+3] / M - mu1*mu1;
  double A1d  = (double)bnw[8+g] / sqrt(var1 + 1e-5);
  double fk   = (double)fkr[0];
  double mu2  = fk * stats[g*6+4] / M;
  double var2 = fk*fk * stats[g*6+5] / M - mu2*mu2;
  double A2d  = (double)bnw[16+g] / sqrt(var2 + 1e-5);
  double Cgd  = ((double)bnb[g] - mu0*A0d) + ((double)bnb[8+g] - mu1*A1d)
              + ((double)bnb[16+g] - mu2*A2d);
  const float A0 = (float)A0d, B2 = (float)(A2d * fk), Cg = (float)Cgd;
  const float B1q = (float)(A1d * fq) * QS[row];

  short* __restrict__ qkrow = QKbf + (size_t)row * 512;
  const float* __restrict__ ksrow = KS + (size_t)bg * 512;
  const int j0 = l * 8;
  bf16x8 qk8 = *(const bf16x8*)(qkrow + j0);
  float4 ks0 = *(const float4*)(ksrow + j0);
  float4 ks1 = *(const float4*)(ksrow + j0 + 4);
  float ks[8] = {ks0.x, ks0.y, ks0.z, ks0.w, ks1.x, ks1.y, ks1.z, ks1.w};
  const float* relq = rel + 511 + c - j0;      // descending in e
  const float* relk = rel + 1534 + j0 - c;     // ascending in e
  float s[8];
  float sum = 0.f;
  #pragma unroll
  for (int e = 0; e < 8; ++e){
    float sc = A0 * bf2f(qk8[e]) + B1q * relq[-e] + B2 * ks[e] * relk[e] + Cg;
    s[e] = __expf(sc);
    sum += s[e];
  }
  #pragma unroll
  for (int off = 32; off; off >>= 1) sum += __shfl_xor(sum, off);
  const float inv = 1.0f / sum;
  const float* relv = rel + 2557 + c - j0;     // descending in e
  float sve = 0.f;
  bf16x8 p8;
  #pragma unroll
  for (int e = 0; e < 8; ++e){
    float p = s[e] * inv;
    p8[e] = f2bf(p);
    sve += p * relv[-e];
  }
  *(bf16x8*)(qkrow + j0) = p8;
  #pragma unroll
  for (int off = 32; off; off >>= 1) sve += __shfl_xor(sve, off);
  if (l == 0){
    float e = fsve[0] * sve;
    SVE[row] = e;
    const int b = bg >> 3;
    atomicAdd(&S12[b * 512 + c],        128.f * e);
    atomicAdd(&S12[4096 + b * 512 + c], 128.f * e * e);
  }
}

// ---------------- K5: SV2[bg][c][j] = bf16(f_sv * sum_i P[c,i] Vt[j,i]) + LN stat partials ---
// Reg-direct MFMA, tile 128(c) x 64(j), grid (2,4,64)=512 blocks (2/CU). Waves 2x2 of 64x32.
__global__ __launch_bounds__(256) void k_sv(const short* __restrict__ Pbf,
                                            const short* __restrict__ Vt,
                                            const float* __restrict__ fsv,
                                            short* __restrict__ SV2,
                                            float* __restrict__ S12){
  const int nt = blockIdx.x, mt = blockIdx.y, bg = blockIdx.z;
  const int t = threadIdx.x, l = t & 63, w = t >> 6;
  const int wr = (w >> 1) * 64, wc = (w & 1) * 32;
  const short* __restrict__ A = Pbf + (size_t)bg * 262144 + (size_t)mt * 128 * 512;
  const short* __restrict__ B = Vt  + (size_t)bg * 65536  + (size_t)nt * 64 * 512;
  f32x4 acc[4][2];
  #pragma unroll
  for (int m = 0; m < 4; ++m)
    #pragma unroll
    for (int n = 0; n < 2; ++n) acc[m][n] = {0.f, 0.f, 0.f, 0.f};
  const int rA = wr + (l & 15), rB = wc + (l & 15);
  const int co = (l >> 4) * 8;
  #pragma unroll 1
  for (int kk = 0; kk < 16; ++kk){
    bf16x8 af[4], bfr[2];
    #pragma unroll
    for (int m = 0; m < 4; ++m)
      af[m] = *(const bf16x8*)(A + (size_t)(rA + m * 16) * 512 + kk * 32 + co);
    #pragma unroll
    for (int n = 0; n < 2; ++n)
      bfr[n] = *(const bf16x8*)(B + (size_t)(rB + n * 16) * 512 + kk * 32 + co);
    #pragma unroll
    for (int m = 0; m < 4; ++m)
      #pragma unroll
      for (int n = 0; n < 2; ++n)
        acc[m][n] = __builtin_amdgcn_mfma_f32_16x16x32_bf16(af[m], bfr[n], acc[m][n], 0, 0, 0);
  }
  __shared__ float s1buf[128], s2buf[128];
  if (t < 128){ s1buf[t] = 0.f; s2buf[t] = 0.f; }
  __syncthreads();
  const float fv = fsv[0];
  short* out = SV2 + (size_t)bg * 65536 + (size_t)(mt * 128 + wr) * 128 + nt * 64 + wc;
  #pragma unroll
  for (int m = 0; m < 4; ++m)
    #pragma unroll
    for (int jr = 0; jr < 4; ++jr){
      float p1 = 0.f, p2 = 0.f;
      #pragma unroll
      for (int n = 0; n < 2; ++n){
        float vl = acc[m][n][jr] * fv;
        p1 += vl; p2 += vl * vl;
        out[(size_t)(m * 16 + (l >> 4) * 4 + jr) * 128 + n * 16 + (l & 15)] = f2bf(vl);
      }
      #pragma unroll
      for (int off = 1; off < 16; off <<= 1){
        p1 += __shfl_xor(p1, off);
        p2 += __shfl_xor(p2, off);
      }
      if ((l & 15) == 0){
        int rloc = wr + m * 16 + (l >> 4) * 4 + jr;
        atomicAdd(&s1buf[rloc], p1);
        atomicAdd(&s2buf[rloc], p2);
      }
    }
  __syncthreads();
  if (t < 128){
    const int b = bg >> 3;
    const int ci = b * 512 + mt * 128 + t;
    atomicAdd(&S12[ci],        s1buf[t]);
    atomicAdd(&S12[4096 + ci], s2buf[t]);
  }
}

// ---------------- K6: normalize + fold + residual; mean/rstd from S12 inline ----------------
__global__ __launch_bounds__(256) void k_out(const short* __restrict__ SV2,
    const float* __restrict__ SVE, const float* __restrict__ S12,
    const float* __restrict__ X, const float* __restrict__ gam, float* __restrict__ OUT){
  const int c2t = blockIdx.x, g = blockIdx.y, b = blockIdx.z;
  const int bg = b * 8 + g;
  const int c20 = c2t * 64;
  __shared__ float s[64][129];
  const int t = threadIdx.x;
  {
    const int col8 = (t & 15) * 8;
    #pragma unroll
    for (int r0 = 0; r0 < 64; r0 += 16){
      int row = r0 + (t >> 4);
      bf16x8 v = *(const bf16x8*)(SV2 + (size_t)bg * 65536 + (size_t)(c20 + row) * 128 + col8);
      #pragma unroll
      for (int e = 0; e < 8; ++e) s[row][col8 + e] = bf2f(v[e]);
    }
  }
  __syncthreads();
  const int lane = t & 63, w = t >> 6;
  const int c2 = c20 + lane;
  const float sm1 = S12[b * 512 + c2];
  const float sm2 = S12[4096 + b * 512 + c2];
  const float mean = sm1 * (1.f / 2048.f);
  const float rs   = rsqrtf(sm2 * (1.f / 2048.f) - mean * mean + 1e-5f);
  const float e    = SVE[(size_t)bg * 512 + c2];
  const float gm   = gam[0];
  for (int j = w; j < 128; j += 4){
    float v = s[lane][j];
    float o = (v + e - 2.f * mean) * rs;
    int chan = g * 64 + (j >> 1);
    size_t oi = ((size_t)b * 512 + chan) * 1024 + ((j & 1) << 9) + c2;
    OUT[oi] = gm * o + X[oi];
  }
}

extern "C" void kernel_launch(void* const* d_in, const int* in_sizes, int n_in,
                              void* d_out, int out_size, void* d_ws, size_t ws_size,
                              hipStream_t stream){
  const float* X    = (const float*)d_in[0];
  const float* W    = (const float*)d_in[1];
  const float* REL  = (const float*)d_in[2];
  const float* BNW  = (const float*)d_in[3];
  const float* BNB  = (const float*)d_in[4];
  const float* FQR  = (const float*)d_in[5];
  const float* FKR  = (const float*)d_in[6];
  const float* FSV  = (const float*)d_in[7];
  const float* FSVE = (const float*)d_in[8];
  const float* GAM  = (const float*)d_in[9];
  float* OUT = (float*)d_out;

  char* ws = (char*)d_ws;
  short*  Ybf   = (short*) (ws + 0ull);          // 25,165,824 B  (8,1536,1024) bf16
  short*  QKbf  = (short*) (ws + 25165824ull);   // 33,554,432 B  (64,512,512) bf16 (qk then P)
  short*  SV2   = (short*) (ws + 58720256ull);   //  8,388,608 B  (64,512,128) bf16 [bg][c][j]
  short*  Wbf   = (short*) (ws + 75497472ull);   //  1,572,864 B
  short*  Xt    = (short*) (ws + 77070336ull);   //  8,388,608 B  (8,1024,512) bf16
  short*  Vt    = (short*) (ws + 85458944ull);   //  8,388,608 B  (64,128,512) bf16
  float*  QS    = (float*) (ws + 93847552ull);   //    131,072 B
  float*  KS    = (float*) (ws + 93978624ull);   //    131,072 B
  float*  SVE   = (float*) (ws + 94109696ull);   //    131,072 B
  double* STATS = (double*)(ws + 94240768ull);   //        384 B (48 doubles)
  float*  S12   = (float*) (ws + 94249472ull);   //     32,768 B (2 x 8*512 fp32)

  k_prep   <<<1792,            256, 0, stream>>>(X, Xt, W, Wbf, STATS, S12);
  k_gemm1  <<<dim3(8, 12, 8),  256, 0, stream>>>(Wbf, Xt, Ybf);
  k_ln     <<<3072,            256, 0, stream>>>(Ybf, QS, KS);
  k_qk     <<<dim3(4, 4, 64),  256, 0, stream>>>(Ybf, QKbf, STATS);
  k_qrkr   <<<64,              256, 0, stream>>>(QS, KS, REL, STATS);
  k_vt     <<<dim3(2, 8, 64),  256, 0, stream>>>(Ybf, Vt);
  k_softmax<<<8192,            256, 0, stream>>>(QKbf, QS, KS, REL, STATS,
                                                 BNW, BNB, FQR, FKR, FSVE, SVE, S12);
  k_sv     <<<dim3(2, 4, 64),  256, 0, stream>>>(QKbf, Vt, FSV, SV2, S12);
  k_out    <<<dim3(8, 8, 8),   256, 0, stream>>>(SV2, SVE, S12, X, GAM, OUT);
}

// Round 10
// 131.791 us; speedup vs baseline: 1.1476x; 1.1476x over previous
//
#include <hip/hip_runtime.h>
#include <math.h>

#define DEV_INLINE __device__ __forceinline__

typedef short bf16x8 __attribute__((ext_vector_type(8)));
typedef float f32x4  __attribute__((ext_vector_type(4)));

// Problem constants: N=8, C=512, HW=1024, OC=3C=1536, G=8, gp=128

DEV_INLINE float bf2f(short h){
  union { unsigned u; float f; } x; x.u = ((unsigned)(unsigned short)h) << 16; return x.f;
}
DEV_INLINE short f2bf(float f){
  union { float f; unsigned u; } x; x.f = f;
  unsigned r = x.u + 0x7FFF + ((x.u >> 16) & 1);
  return (short)(r >> 16);
}

// ---------------- block reduction helpers (blockDim == 256) ----------------
template<bool MAXOP>
DEV_INLINE float block_reduce_f(float v){
  __shared__ float tmp[4];
  const int lane = threadIdx.x & 63, w = threadIdx.x >> 6;
  #pragma unroll
  for (int off = 32; off; off >>= 1){
    float o = __shfl_down(v, off);
    v = MAXOP ? fmaxf(v, o) : (v + o);
  }
  __syncthreads();
  if (lane == 0) tmp[w] = v;
  __syncthreads();
  return MAXOP ? fmaxf(fmaxf(tmp[0], tmp[1]), fmaxf(tmp[2], tmp[3]))
               : (tmp[0] + tmp[1] + tmp[2] + tmp[3]);
}

DEV_INLINE double block_reduce_d(double v){
  __shared__ double tmp[4];
  const int lane = threadIdx.x & 63, w = threadIdx.x >> 6;
  #pragma unroll
  for (int off = 32; off; off >>= 1) v += __shfl_down(v, off);
  __syncthreads();
  if (lane == 0) tmp[w] = v;
  __syncthreads();
  return tmp[0] + tmp[1] + tmp[2] + tmp[3];
}

// ---------------- MFMA tile machinery (single-buffer; m99/m100: explicit dbuf
// doesn't help this structure; R9: reg-direct MFMA regresses — LDS stage decouples
// the load->MFMA chain and this is the local optimum) ----------------
// LDS tile: 128 rows x 32 bf16 cols (64B rows), XOR-swizzled.

DEV_INLINE void stage_tile(const short* __restrict__ g, int ldk, char* lds_region, int t){
  #pragma unroll
  for (int r = 0; r < 2; ++r){
    int o   = t * 16 + r * 4096;
    int row = o >> 6, wb = o & 63;
    int swb = wb ^ (((row >> 1) & 3) << 4);
    const short* src = g + (size_t)row * ldk + (swb >> 1);
    char* dst = lds_region + ((t >> 6) << 10) + (r << 12); // wave-uniform
    __builtin_amdgcn_global_load_lds((const __attribute__((address_space(1))) void*)src,
                                     (__attribute__((address_space(3))) void*)dst, 16, 0, 0);
  }
}

DEV_INLINE bf16x8 read_frag(const char* base, int row, int kgrp){
  int off = row * 64 + ((kgrp ^ ((row >> 1) & 3)) << 4);
  return *(const bf16x8*)(base + off);
}

// A: row-major [M][K] bf16, B^T: row-major [N][K] bf16 (both K-contiguous).
// Block: 256 thr = 4 waves (2x2 of 64x64), tile 128x128, BK=32.
template<int KTILES>
DEV_INLINE void mfma_loop(const short* __restrict__ A, int ldA,
                          const short* __restrict__ B, int ldB,
                          char* ldsA, char* ldsB, int t, f32x4 acc[4][4]){
  const int l = t & 63, w = t >> 6;
  const int wr = (w >> 1) * 64, wc = (w & 1) * 64;
  for (int kt = 0; kt < KTILES; ++kt){
    stage_tile(A + kt * 32, ldA, ldsA, t);
    stage_tile(B + kt * 32, ldB, ldsB, t);
    __syncthreads();
    bf16x8 af[4], bfr[4];
    #pragma unroll
    for (int m = 0; m < 4; ++m) af[m]  = read_frag(ldsA, wr + m * 16 + (l & 15), l >> 4);
    #pragma unroll
    for (int n = 0; n < 4; ++n) bfr[n] = read_frag(ldsB, wc + n * 16 + (l & 15), l >> 4);
    #pragma unroll
    for (int m = 0; m < 4; ++m)
      #pragma unroll
      for (int n = 0; n < 4; ++n)
        acc[m][n] = __builtin_amdgcn_mfma_f32_16x16x32_bf16(af[m], bfr[n], acc[m][n], 0, 0, 0);
    __syncthreads();
  }
}

// ---------------- K0: combined prep — Xt transpose-convert + W convert + zeroing ------
__global__ __launch_bounds__(256) void k_prep(const float* __restrict__ X, short* __restrict__ Xt,
                                              const float* __restrict__ W, short* __restrict__ Wbf,
                                              double* __restrict__ stats, float* __restrict__ S12){
  __shared__ short s[64][72];
  const int bid = blockIdx.x;
  const int t = threadIdx.x;
  if (bid < 1024){
    const int it = bid & 15, kt = (bid >> 4) & 7, b = bid >> 7;
    const int rl = t >> 2, cs = (t & 3) * 16;
    const float* src = X + ((size_t)b * 512 + kt * 64 + rl) * 1024 + it * 64 + cs;
    #pragma unroll
    for (int e = 0; e < 16; e += 4){
      float4 v = *(const float4*)(src + e);
      s[rl][cs + e + 0] = f2bf(v.x); s[rl][cs + e + 1] = f2bf(v.y);
      s[rl][cs + e + 2] = f2bf(v.z); s[rl][cs + e + 3] = f2bf(v.w);
    }
    __syncthreads();
    bf16x8 a0, a1;
    #pragma unroll
    for (int e = 0; e < 8; ++e){ a0[e] = s[cs + e][rl]; a1[e] = s[cs + 8 + e][rl]; }
    short* dst = Xt + ((size_t)b * 1024 + it * 64 + rl) * 512 + kt * 64 + cs;
    *(bf16x8*)dst = a0;
    *(bf16x8*)(dst + 8) = a1;
  } else {
    const int gi = (bid - 1024) * 256 + t;
    if (gi < 48) stats[gi] = 0.0;
    if (gi < 8192) S12[gi] = 0.f;
    const int i = gi * 4;
    float4 v = *(const float4*)(W + i);
    short4 o; o.x = f2bf(v.x); o.y = f2bf(v.y); o.z = f2bf(v.z); o.w = f2bf(v.w);
    *(short4*)(Wbf + i) = o;
  }
}

// V (per bg: Ybf rows [b*1536+g*192+128, +64) viewed [512][128]) -> Vt [bg][128][512]
__global__ __launch_bounds__(256) void k_vt(const short* __restrict__ Ybf, short* __restrict__ Vt){
  const int bg = blockIdx.z, iit = blockIdx.y, jt = blockIdx.x;
  const int b = bg >> 3, g = bg & 7;
  const short* V = Ybf + (size_t)(b * 1536 + g * 192 + 128) * 1024;
  __shared__ short s[64][72];
  const int t = threadIdx.x;
  const int rl = t >> 2, cs = (t & 3) * 16;
  const short* src = V + (size_t)(iit * 64 + rl) * 128 + jt * 64 + cs;
  *(bf16x8*)&s[rl][cs]     = *(const bf16x8*)src;
  *(bf16x8*)&s[rl][cs + 8] = *(const bf16x8*)(src + 8);
  __syncthreads();
  bf16x8 a0, a1;
  #pragma unroll
  for (int e = 0; e < 8; ++e){ a0[e] = s[cs + e][rl]; a1[e] = s[cs + 8 + e][rl]; }
  short* dst = Vt + ((size_t)bg * 128 + jt * 64 + rl) * 512 + iit * 64 + cs;
  *(bf16x8*)dst = a0;
  *(bf16x8*)(dst + 8) = a1;
}

// ---------------- K1: Ybf = bf16( W @ X ), pre-LN ----------------
__global__ __launch_bounds__(256) void k_gemm1(const short* __restrict__ Wbf,
                                               const short* __restrict__ Xt,
                                               short* __restrict__ Ybf){
  const int b = blockIdx.z, mt = blockIdx.y, nt = blockIdx.x;
  __shared__ char lds[16384];
  const int t = threadIdx.x;
  f32x4 acc[4][4];
  #pragma unroll
  for (int m = 0; m < 4; ++m)
    #pragma unroll
    for (int n = 0; n < 4; ++n) acc[m][n] = {0.f, 0.f, 0.f, 0.f};
  const short* A = Wbf + (size_t)mt * 128 * 512;
  const short* B = Xt + (size_t)b * 1024 * 512 + (size_t)nt * 128 * 512;
  mfma_loop<16>(A, 512, B, 512, lds, lds + 8192, t, acc);
  const int l = t & 63, w = t >> 6, wr = (w >> 1) * 64, wc = (w & 1) * 64;
  short* out = Ybf + (size_t)b * 1536 * 1024 + (size_t)(mt * 128 + wr) * 1024 + nt * 128 + wc;
  #pragma unroll
  for (int m = 0; m < 4; ++m)
    #pragma unroll
    for (int n = 0; n < 4; ++n)
      #pragma unroll
      for (int j = 0; j < 4; ++j)
        out[(size_t)(m * 16 + (l >> 4) * 4 + j) * 1024 + n * 16 + (l & 15)] = f2bf(acc[m][n][j]);
}

// ---------------- K1b: wave-per-row LN of Ybf (1024 cols) + q/k chunk sums ----------------
__global__ __launch_bounds__(256) void k_ln(short* __restrict__ Ybf,
                                            float* __restrict__ QS, float* __restrict__ KS){
  const int row = blockIdx.x * 4 + (threadIdx.x >> 6);   // b*1536 + o
  const int l = threadIdx.x & 63;
  short* p = Ybf + (size_t)row * 1024 + l * 16;
  bf16x8 v0 = *(const bf16x8*)p;
  bf16x8 v1 = *(const bf16x8*)(p + 8);
  float f[16];
  #pragma unroll
  for (int e = 0; e < 8; ++e){ f[e] = bf2f(v0[e]); f[8 + e] = bf2f(v1[e]); }
  float s1 = 0.f, s2 = 0.f;
  #pragma unroll
  for (int e = 0; e < 16; ++e){ s1 += f[e]; s2 += f[e] * f[e]; }
  #pragma unroll
  for (int off = 32; off; off >>= 1){ s1 += __shfl_xor(s1, off); s2 += __shfl_xor(s2, off); }
  float mean = s1 * (1.f / 1024.f);
  float r = rsqrtf(s2 * (1.f / 1024.f) - mean * mean + 1e-5f);
  float cs = 0.f;
  #pragma unroll
  for (int e = 0; e < 16; ++e){ f[e] = (f[e] - mean) * r; cs += f[e]; }
  bf16x8 o0, o1;
  #pragma unroll
  for (int e = 0; e < 8; ++e){ o0[e] = f2bf(f[e]); o1[e] = f2bf(f[8 + e]); }
  *(bf16x8*)p = o0;
  *(bf16x8*)(p + 8) = o1;
  // chunk sums: chunk = l>>3 (128 elems = 8 lanes x 16)
  cs += __shfl_xor(cs, 1); cs += __shfl_xor(cs, 2); cs += __shfl_xor(cs, 4);
  const int o = row % 1536, ol = o % 192;
  if ((l & 7) == 0 && ol < 128){
    const int b = row / 1536, g = o / 192;
    const int c = (ol & 63) * 8 + (l >> 3);
    const int idx = (b * 8 + g) * 512 + c;
    if (ol < 64) QS[idx] = cs; else KS[idx] = cs;
  }
}

// ---------------- K2: QKbf = bf16( q @ k^T ) + per-g sum/sumsq ----------------
__global__ __launch_bounds__(256) void k_qk(const short* __restrict__ Ybf,
                                            short* __restrict__ QKbf,
                                            double* __restrict__ stats){
  const int bg = blockIdx.z, mt = blockIdx.y, nt = blockIdx.x;
  const int b = bg >> 3, g = bg & 7;
  __shared__ char lds[16384];
  const int t = threadIdx.x;
  f32x4 acc[4][4];
  #pragma unroll
  for (int m = 0; m < 4; ++m)
    #pragma unroll
    for (int n = 0; n < 4; ++n) acc[m][n] = {0.f, 0.f, 0.f, 0.f};
  const short* q  = Ybf + (size_t)(b * 1536 + g * 192) * 1024;
  const short* kp = q + 65536;
  mfma_loop<4>(q + (size_t)mt * 128 * 128, 128, kp + (size_t)nt * 128 * 128, 128,
               lds, lds + 8192, t, acc);
  const int l = t & 63, w = t >> 6, wr = (w >> 1) * 64, wc = (w & 1) * 64;
  short* out = QKbf + (size_t)bg * 512 * 512 + (size_t)(mt * 128 + wr) * 512 + nt * 128 + wc;
  float s1 = 0.f, s2 = 0.f;
  #pragma unroll
  for (int m = 0; m < 4; ++m)
    #pragma unroll
    for (int n = 0; n < 4; ++n)
      #pragma unroll
      for (int j = 0; j < 4; ++j){
        float vl = acc[m][n][j];
        s1 += vl; s2 += vl * vl;
        out[(size_t)(m * 16 + (l >> 4) * 4 + j) * 512 + n * 16 + (l & 15)] = f2bf(vl);
      }
  float S1 = block_reduce_f<false>(s1);
  float S2 = block_reduce_f<false>(s2);
  if (t == 0){
    atomicAdd(&stats[g * 6 + 0], (double)S1);
    atomicAdd(&stats[g * 6 + 1], (double)S2);
  }
}

// ---------------- K3: qr/kr closed-form stats; 64 blocks (g x 8 c-chunks) ----------------
__global__ __launch_bounds__(256) void k_qrkr(const float* __restrict__ QS,
                                              const float* __restrict__ KS,
                                              const float* __restrict__ rel,
                                              double* __restrict__ stats){
  const int g = blockIdx.x & 7, ch = blockIdx.x >> 3;
  const int t = threadIdx.x;
  const int c = ch * 64 + (t >> 2), part = t & 3;
  float r1 = 0, r2 = 0, r3 = 0, r4 = 0;
  for (int d = part * 128; d < part * 128 + 128; ++d){
    float v0 = rel[c + d];        r1 += v0; r2 += v0 * v0;
    float v1 = rel[1023 + c + d]; r3 += v1; r4 += v1 * v1;
  }
  #pragma unroll
  for (int off = 1; off < 4; off <<= 1){
    r1 += __shfl_xor(r1, off); r2 += __shfl_xor(r2, off);
    r3 += __shfl_xor(r3, off); r4 += __shfl_xor(r4, off);
  }
  double sq1 = 0, sq2 = 0, sk1 = 0, sk2 = 0;
  if (part == 0){
    float qa = 0, qb = 0, ka = 0, kb = 0;
    for (int b = 0; b < 8; ++b){
      float v = QS[(size_t)(b * 8 + g) * 512 + c]; qa += v; qb += v * v;
      float w = KS[(size_t)(b * 8 + g) * 512 + c]; ka += w; kb += w * w;
    }
    sq1 = (double)r1 * qa; sq2 = (double)r2 * qb;
    sk1 = (double)r3 * ka; sk2 = (double)r4 * kb;
  }
  sq1 = block_reduce_d(sq1);
  sq2 = block_reduce_d(sq2);
  sk1 = block_reduce_d(sk1);
  sk2 = block_reduce_d(sk2);
  if (t == 0){
    atomicAdd(&stats[g * 6 + 2], sq1);
    atomicAdd(&stats[g * 6 + 3], sq2);
    atomicAdd(&stats[g * 6 + 4], sk1);
    atomicAdd(&stats[g * 6 + 5], sk2);
  }
}

// ---------------- fused BN + sum + softmax + sve; wave per row, no syncs ----------------
// No max subtraction: s is a sum of 3 BN-standardized fields (|s| ~ 20), exp fp32-safe —
// validated in R7/R9 (absmax bit-identical to max-subtracted version).
__global__ __launch_bounds__(256) void k_softmax(short* __restrict__ QKbf,
    const float* __restrict__ QS, const float* __restrict__ KS,
    const float* __restrict__ rel, const double* __restrict__ stats,
    const float* __restrict__ bnw, const float* __restrict__ bnb,
    const float* __restrict__ fqr, const float* __restrict__ fkr,
    const float* __restrict__ fsve, float* __restrict__ SVE, float* __restrict__ S12){
  const int row = blockIdx.x * 4 + (threadIdx.x >> 6);   // (b*8+g)*512 + c
  const int l = threadIdx.x & 63;
  const int bg = row >> 9, c = row & 511, g = bg & 7;
  // inline BN coefficients (uniform per block)
  const double M = 2097152.0; // 8*512*512
  double mu0  = stats[g*6+0] / M;
  double var0 = stats[g*6+1] / M - mu0*mu0;
  double A0d  = (double)bnw[g] / sqrt(var0 + 1e-5);
  double fq   = (double)fqr[0];
  double mu1  = fq * stats[g*6+2] / M;
  double var1 = fq*fq * stats[g*6+3] / M - mu1*mu1;
  double A1d  = (double)bnw[8+g] / sqrt(var1 + 1e-5);
  double fk   = (double)fkr[0];
  double mu2  = fk * stats[g*6+4] / M;
  double var2 = fk*fk * stats[g*6+5] / M - mu2*mu2;
  double A2d  = (double)bnw[16+g] / sqrt(var2 + 1e-5);
  double Cgd  = ((double)bnb[g] - mu0*A0d) + ((double)bnb[8+g] - mu1*A1d)
              + ((double)bnb[16+g] - mu2*A2d);
  const float A0 = (float)A0d, B2 = (float)(A2d * fk), Cg = (float)Cgd;
  const float B1q = (float)(A1d * fq) * QS[row];

  short* __restrict__ qkrow = QKbf + (size_t)row * 512;
  const float* __restrict__ ksrow = KS + (size_t)bg * 512;
  const int j0 = l * 8;
  bf16x8 qk8 = *(const bf16x8*)(qkrow + j0);
  float4 ks0 = *(const float4*)(ksrow + j0);
  float4 ks1 = *(const float4*)(ksrow + j0 + 4);
  float ks[8] = {ks0.x, ks0.y, ks0.z, ks0.w, ks1.x, ks1.y, ks1.z, ks1.w};
  const float* relq = rel + 511 + c - j0;      // descending in e
  const float* relk = rel + 1534 + j0 - c;     // ascending in e
  float s[8];
  float sum = 0.f;
  #pragma unroll
  for (int e = 0; e < 8; ++e){
    float sc = A0 * bf2f(qk8[e]) + B1q * relq[-e] + B2 * ks[e] * relk[e] + Cg;
    s[e] = __expf(sc);
    sum += s[e];
  }
  #pragma unroll
  for (int off = 32; off; off >>= 1) sum += __shfl_xor(sum, off);
  const float inv = 1.0f / sum;
  const float* relv = rel + 2557 + c - j0;     // descending in e
  float sve = 0.f;
  bf16x8 p8;
  #pragma unroll
  for (int e = 0; e < 8; ++e){
    float p = s[e] * inv;
    p8[e] = f2bf(p);
    sve += p * relv[-e];
  }
  *(bf16x8*)(qkrow + j0) = p8;
  #pragma unroll
  for (int off = 32; off; off >>= 1) sve += __shfl_xor(sve, off);
  if (l == 0){
    float e = fsve[0] * sve;
    SVE[row] = e;
    const int b = bg >> 3;
    atomicAdd(&S12[b * 512 + c],        128.f * e);
    atomicAdd(&S12[4096 + b * 512 + c], 128.f * e * e);
  }
}

// ---------------- K5: SV2[bg][c][j] = bf16(f_sv * sum_i P[c,i] Vt[j,i]) + LN stat partials ---
__global__ __launch_bounds__(256) void k_sv(const short* __restrict__ Pbf,
                                            const short* __restrict__ Vt,
                                            const float* __restrict__ fsv,
                                            short* __restrict__ SV2,
                                            float* __restrict__ S12){
  const int bg = blockIdx.z, mt = blockIdx.x;   // M=512 (c): 4 tiles; N=128 (j): 1 tile
  __shared__ char lds[16384];
  __shared__ float s1buf[128], s2buf[128];
  const int t = threadIdx.x;
  s1buf[t & 127] = 0.f; s2buf[t & 127] = 0.f;   // pre-loop sync happens inside mfma_loop
  f32x4 acc[4][4];
  #pragma unroll
  for (int m = 0; m < 4; ++m)
    #pragma unroll
    for (int n = 0; n < 4; ++n) acc[m][n] = {0.f, 0.f, 0.f, 0.f};
  const short* A = Pbf + (size_t)bg * 512 * 512 + (size_t)mt * 128 * 512;
  const short* B = Vt  + (size_t)bg * 128 * 512;
  mfma_loop<16>(A, 512, B, 512, lds, lds + 8192, t, acc);
  const int l = t & 63, w = t >> 6, wr = (w >> 1) * 64, wc = (w & 1) * 64;
  const float fv = fsv[0];
  short* out = SV2 + (size_t)bg * 512 * 128 + (size_t)(mt * 128 + wr) * 128 + wc;
  #pragma unroll
  for (int m = 0; m < 4; ++m)
    #pragma unroll
    for (int jr = 0; jr < 4; ++jr){
      float p1 = 0.f, p2 = 0.f;
      #pragma unroll
      for (int n = 0; n < 4; ++n){
        float vl = acc[m][n][jr] * fv;
        p1 += vl; p2 += vl * vl;
        out[(size_t)(m * 16 + (l >> 4) * 4 + jr) * 128 + n * 16 + (l & 15)] = f2bf(vl);
      }
      #pragma unroll
      for (int off = 1; off < 16; off <<= 1){
        p1 += __shfl_xor(p1, off);
        p2 += __shfl_xor(p2, off);
      }
      if ((l & 15) == 0){
        int rloc = wr + m * 16 + (l >> 4) * 4 + jr;
        atomicAdd(&s1buf[rloc], p1);
        atomicAdd(&s2buf[rloc], p2);
      }
    }
  __syncthreads();
  if (t < 128){
    const int b = bg >> 3;
    const int ci = b * 512 + mt * 128 + t;
    atomicAdd(&S12[ci],        s1buf[t]);
    atomicAdd(&S12[4096 + ci], s2buf[t]);
  }
}

// ---------------- K6: normalize + fold + residual; mean/rstd from S12 inline ----------------
__global__ __launch_bounds__(256) void k_out(const short* __restrict__ SV2,
    const float* __restrict__ SVE, const float* __restrict__ S12,
    const float* __restrict__ X, const float* __restrict__ gam, float* __restrict__ OUT){
  const int c2t = blockIdx.x, g = blockIdx.y, b = blockIdx.z;
  const int bg = b * 8 + g;
  const int c20 = c2t * 64;
  __shared__ float s[64][129];
  const int t = threadIdx.x;
  {
    const int col8 = (t & 15) * 8;
    #pragma unroll
    for (int r0 = 0; r0 < 64; r0 += 16){
      int row = r0 + (t >> 4);
      bf16x8 v = *(const bf16x8*)(SV2 + (size_t)bg * 65536 + (size_t)(c20 + row) * 128 + col8);
      #pragma unroll
      for (int e = 0; e < 8; ++e) s[row][col8 + e] = bf2f(v[e]);
    }
  }
  __syncthreads();
  const int lane = t & 63, w = t >> 6;
  const int c2 = c20 + lane;
  const float sm1 = S12[b * 512 + c2];
  const float sm2 = S12[4096 + b * 512 + c2];
  const float mean = sm1 * (1.f / 2048.f);
  const float rs   = rsqrtf(sm2 * (1.f / 2048.f) - mean * mean + 1e-5f);
  const float e    = SVE[(size_t)bg * 512 + c2];
  const float gm   = gam[0];
  for (int j = w; j < 128; j += 4){
    float v = s[lane][j];
    float o = (v + e - 2.f * mean) * rs;
    int chan = g * 64 + (j >> 1);
    size_t oi = ((size_t)b * 512 + chan) * 1024 + ((j & 1) << 9) + c2;
    OUT[oi] = gm * o + X[oi];
  }
}

extern "C" void kernel_launch(void* const* d_in, const int* in_sizes, int n_in,
                              void* d_out, int out_size, void* d_ws, size_t ws_size,
                              hipStream_t stream){
  const float* X    = (const float*)d_in[0];
  const float* W    = (const float*)d_in[1];
  const float* REL  = (const float*)d_in[2];
  const float* BNW  = (const float*)d_in[3];
  const float* BNB  = (const float*)d_in[4];
  const float* FQR  = (const float*)d_in[5];
  const float* FKR  = (const float*)d_in[6];
  const float* FSV  = (const float*)d_in[7];
  const float* FSVE = (const float*)d_in[8];
  const float* GAM  = (const float*)d_in[9];
  float* OUT = (float*)d_out;

  char* ws = (char*)d_ws;
  short*  Ybf   = (short*) (ws + 0ull);          // 25,165,824 B  (8,1536,1024) bf16
  short*  QKbf  = (short*) (ws + 25165824ull);   // 33,554,432 B  (64,512,512) bf16 (qk then P)
  short*  SV2   = (short*) (ws + 58720256ull);   //  8,388,608 B  (64,512,128) bf16 [bg][c][j]
  short*  Wbf   = (short*) (ws + 75497472ull);   //  1,572,864 B
  short*  Xt    = (short*) (ws + 77070336ull);   //  8,388,608 B  (8,1024,512) bf16
  short*  Vt    = (short*) (ws + 85458944ull);   //  8,388,608 B  (64,128,512) bf16
  float*  QS    = (float*) (ws + 93847552ull);   //    131,072 B
  float*  KS    = (float*) (ws + 93978624ull);   //    131,072 B
  float*  SVE   = (float*) (ws + 94109696ull);   //    131,072 B
  double* STATS = (double*)(ws + 94240768ull);   //        384 B (48 doubles)
  float*  S12   = (float*) (ws + 94249472ull);   //     32,768 B (2 x 8*512 fp32)

  k_prep   <<<1792,            256, 0, stream>>>(X, Xt, W, Wbf, STATS, S12);
  k_gemm1  <<<dim3(8, 12, 8),  256, 0, stream>>>(Wbf, Xt, Ybf);
  k_ln     <<<3072,            256, 0, stream>>>(Ybf, QS, KS);
  k_qk     <<<dim3(4, 4, 64),  256, 0, stream>>>(Ybf, QKbf, STATS);
  k_qrkr   <<<64,              256, 0, stream>>>(QS, KS, REL, STATS);
  k_vt     <<<dim3(2, 8, 64),  256, 0, stream>>>(Ybf, Vt);
  k_softmax<<<8192,            256, 0, stream>>>(QKbf, QS, KS, REL, STATS,
                                                 BNW, BNB, FQR, FKR, FSVE, SVE, S12);
  k_sv     <<<dim3(4, 1, 64),  256, 0, stream>>>(QKbf, Vt, FSV, SV2, S12);
  k_out    <<<dim3(8, 8, 8),   256, 0, stream>>>(SV2, SVE, S12, X, GAM, OUT);
}

// Round 11
// 118.335 us; speedup vs baseline: 1.2781x; 1.1137x over previous
//
#include <hip/hip_runtime.h>
#include <math.h>

#define DEV_INLINE __device__ __forceinline__

typedef short bf16x8 __attribute__((ext_vector_type(8)));
typedef float f32x4  __attribute__((ext_vector_type(4)));

// Problem constants: N=8, C=512, HW=1024, OC=3C=1536, G=8, gp=128

DEV_INLINE float bf2f(short h){
  union { unsigned u; float f; } x; x.u = ((unsigned)(unsigned short)h) << 16; return x.f;
}
DEV_INLINE short f2bf(float f){
  union { float f; unsigned u; } x; x.f = f;
  unsigned r = x.u + 0x7FFF + ((x.u >> 16) & 1);
  return (short)(r >> 16);
}

// ---------------- block reduction helpers (blockDim == 256) ----------------
template<bool MAXOP>
DEV_INLINE float block_reduce_f(float v){
  __shared__ float tmp[4];
  const int lane = threadIdx.x & 63, w = threadIdx.x >> 6;
  #pragma unroll
  for (int off = 32; off; off >>= 1){
    float o = __shfl_down(v, off);
    v = MAXOP ? fmaxf(v, o) : (v + o);
  }
  __syncthreads();
  if (lane == 0) tmp[w] = v;
  __syncthreads();
  return MAXOP ? fmaxf(fmaxf(tmp[0], tmp[1]), fmaxf(tmp[2], tmp[3]))
               : (tmp[0] + tmp[1] + tmp[2] + tmp[3]);
}

DEV_INLINE double block_reduce_d(double v){
  __shared__ double tmp[4];
  const int lane = threadIdx.x & 63, w = threadIdx.x >> 6;
  #pragma unroll
  for (int off = 32; off; off >>= 1) v += __shfl_down(v, off);
  __syncthreads();
  if (lane == 0) tmp[w] = v;
  __syncthreads();
  return tmp[0] + tmp[1] + tmp[2] + tmp[3];
}

// ---------------- MFMA tile machinery (single-buffer; m99/m100: explicit dbuf
// doesn't help this structure; R9: reg-direct MFMA regresses — LDS stage decouples
// the load->MFMA chain and this is the local optimum) ----------------
// LDS tile: 128 rows x 32 bf16 cols (64B rows), XOR-swizzled.

DEV_INLINE void stage_tile(const short* __restrict__ g, int ldk, char* lds_region, int t){
  #pragma unroll
  for (int r = 0; r < 2; ++r){
    int o   = t * 16 + r * 4096;
    int row = o >> 6, wb = o & 63;
    int swb = wb ^ (((row >> 1) & 3) << 4);
    const short* src = g + (size_t)row * ldk + (swb >> 1);
    char* dst = lds_region + ((t >> 6) << 10) + (r << 12); // wave-uniform
    __builtin_amdgcn_global_load_lds((const __attribute__((address_space(1))) void*)src,
                                     (__attribute__((address_space(3))) void*)dst, 16, 0, 0);
  }
}

DEV_INLINE bf16x8 read_frag(const char* base, int row, int kgrp){
  int off = row * 64 + ((kgrp ^ ((row >> 1) & 3)) << 4);
  return *(const bf16x8*)(base + off);
}

// A: row-major [M][K] bf16, B^T: row-major [N][K] bf16 (both K-contiguous).
// Block: 256 thr = 4 waves (2x2 of 64x64), tile 128x128, BK=32.
template<int KTILES>
DEV_INLINE void mfma_loop(const short* __restrict__ A, int ldA,
                          const short* __restrict__ B, int ldB,
                          char* ldsA, char* ldsB, int t, f32x4 acc[4][4]){
  const int l = t & 63, w = t >> 6;
  const int wr = (w >> 1) * 64, wc = (w & 1) * 64;
  for (int kt = 0; kt < KTILES; ++kt){
    stage_tile(A + kt * 32, ldA, ldsA, t);
    stage_tile(B + kt * 32, ldB, ldsB, t);
    __syncthreads();
    bf16x8 af[4], bfr[4];
    #pragma unroll
    for (int m = 0; m < 4; ++m) af[m]  = read_frag(ldsA, wr + m * 16 + (l & 15), l >> 4);
    #pragma unroll
    for (int n = 0; n < 4; ++n) bfr[n] = read_frag(ldsB, wc + n * 16 + (l & 15), l >> 4);
    #pragma unroll
    for (int m = 0; m < 4; ++m)
      #pragma unroll
      for (int n = 0; n < 4; ++n)
        acc[m][n] = __builtin_amdgcn_mfma_f32_16x16x32_bf16(af[m], bfr[n], acc[m][n], 0, 0, 0);
    __syncthreads();
  }
}

// ---------------- K0: combined prep — Xt transpose-convert + W convert + zeroing ------
__global__ __launch_bounds__(256) void k_prep(const float* __restrict__ X, short* __restrict__ Xt,
                                              const float* __restrict__ W, short* __restrict__ Wbf,
                                              double* __restrict__ stats, float* __restrict__ S12){
  __shared__ short s[64][72];
  const int bid = blockIdx.x;
  const int t = threadIdx.x;
  if (bid < 1024){
    const int it = bid & 15, kt = (bid >> 4) & 7, b = bid >> 7;
    const int rl = t >> 2, cs = (t & 3) * 16;
    const float* src = X + ((size_t)b * 512 + kt * 64 + rl) * 1024 + it * 64 + cs;
    #pragma unroll
    for (int e = 0; e < 16; e += 4){
      float4 v = *(const float4*)(src + e);
      s[rl][cs + e + 0] = f2bf(v.x); s[rl][cs + e + 1] = f2bf(v.y);
      s[rl][cs + e + 2] = f2bf(v.z); s[rl][cs + e + 3] = f2bf(v.w);
    }
    __syncthreads();
    bf16x8 a0, a1;
    #pragma unroll
    for (int e = 0; e < 8; ++e){ a0[e] = s[cs + e][rl]; a1[e] = s[cs + 8 + e][rl]; }
    short* dst = Xt + ((size_t)b * 1024 + it * 64 + rl) * 512 + kt * 64 + cs;
    *(bf16x8*)dst = a0;
    *(bf16x8*)(dst + 8) = a1;
  } else {
    const int gi = (bid - 1024) * 256 + t;
    if (gi < 48) stats[gi] = 0.0;
    if (gi < 8192) S12[gi] = 0.f;
    const int i = gi * 4;
    float4 v = *(const float4*)(W + i);
    short4 o; o.x = f2bf(v.x); o.y = f2bf(v.y); o.z = f2bf(v.z); o.w = f2bf(v.w);
    *(short4*)(Wbf + i) = o;
  }
}

// ---------------- K1: Ybf = bf16( W @ X ), pre-LN ----------------
__global__ __launch_bounds__(256) void k_gemm1(const short* __restrict__ Wbf,
                                               const short* __restrict__ Xt,
                                               short* __restrict__ Ybf){
  const int b = blockIdx.z, mt = blockIdx.y, nt = blockIdx.x;
  __shared__ char lds[16384];
  const int t = threadIdx.x;
  f32x4 acc[4][4];
  #pragma unroll
  for (int m = 0; m < 4; ++m)
    #pragma unroll
    for (int n = 0; n < 4; ++n) acc[m][n] = {0.f, 0.f, 0.f, 0.f};
  const short* A = Wbf + (size_t)mt * 128 * 512;
  const short* B = Xt + (size_t)b * 1024 * 512 + (size_t)nt * 128 * 512;
  mfma_loop<16>(A, 512, B, 512, lds, lds + 8192, t, acc);
  const int l = t & 63, w = t >> 6, wr = (w >> 1) * 64, wc = (w & 1) * 64;
  short* out = Ybf + (size_t)b * 1536 * 1024 + (size_t)(mt * 128 + wr) * 1024 + nt * 128 + wc;
  #pragma unroll
  for (int m = 0; m < 4; ++m)
    #pragma unroll
    for (int n = 0; n < 4; ++n)
      #pragma unroll
      for (int j = 0; j < 4; ++j)
        out[(size_t)(m * 16 + (l >> 4) * 4 + j) * 1024 + n * 16 + (l & 15)] = f2bf(acc[m][n][j]);
}

// ---------------- K1b: wave-per-row LN of Ybf (1024 cols) + q/k chunk sums ----------------
__global__ __launch_bounds__(256) void k_ln(short* __restrict__ Ybf,
                                            float* __restrict__ QS, float* __restrict__ KS){
  const int row = blockIdx.x * 4 + (threadIdx.x >> 6);   // b*1536 + o
  const int l = threadIdx.x & 63;
  short* p = Ybf + (size_t)row * 1024 + l * 16;
  bf16x8 v0 = *(const bf16x8*)p;
  bf16x8 v1 = *(const bf16x8*)(p + 8);
  float f[16];
  #pragma unroll
  for (int e = 0; e < 8; ++e){ f[e] = bf2f(v0[e]); f[8 + e] = bf2f(v1[e]); }
  float s1 = 0.f, s2 = 0.f;
  #pragma unroll
  for (int e = 0; e < 16; ++e){ s1 += f[e]; s2 += f[e] * f[e]; }
  #pragma unroll
  for (int off = 32; off; off >>= 1){ s1 += __shfl_xor(s1, off); s2 += __shfl_xor(s2, off); }
  float mean = s1 * (1.f / 1024.f);
  float r = rsqrtf(s2 * (1.f / 1024.f) - mean * mean + 1e-5f);
  float cs = 0.f;
  #pragma unroll
  for (int e = 0; e < 16; ++e){ f[e] = (f[e] - mean) * r; cs += f[e]; }
  bf16x8 o0, o1;
  #pragma unroll
  for (int e = 0; e < 8; ++e){ o0[e] = f2bf(f[e]); o1[e] = f2bf(f[8 + e]); }
  *(bf16x8*)p = o0;
  *(bf16x8*)(p + 8) = o1;
  // chunk sums: chunk = l>>3 (128 elems = 8 lanes x 16)
  cs += __shfl_xor(cs, 1); cs += __shfl_xor(cs, 2); cs += __shfl_xor(cs, 4);
  const int o = row % 1536, ol = o % 192;
  if ((l & 7) == 0 && ol < 128){
    const int b = row / 1536, g = o / 192;
    const int c = (ol & 63) * 8 + (l >> 3);
    const int idx = (b * 8 + g) * 512 + c;
    if (ol < 64) QS[idx] = cs; else KS[idx] = cs;
  }
}

// ---------------- K2: merged mid-stage — qrkr stats | qk GEMM | V transpose ----------------
// All three depend only on k_ln outputs and are mutually independent; one dispatch
// replaces three (launch overhead ~1.8us each, measured R8) and lets small blocks
// fill CUs alongside the qk MFMA blocks.
// blockIdx.x: [0,64) qrkr | [64,1088) qk | [1088,2112) vt
__global__ __launch_bounds__(256) void k_mid(const short* __restrict__ Ybf,
                                             short* __restrict__ QKbf,
                                             short* __restrict__ Vt,
                                             const float* __restrict__ QS,
                                             const float* __restrict__ KS,
                                             const float* __restrict__ rel,
                                             double* __restrict__ stats){
  __shared__ char lds[16384];
  const int bid = blockIdx.x;
  const int t = threadIdx.x;

  if (bid < 64){
    // ---- qr/kr closed-form stats (g x 8 c-chunks) ----
    const int g = bid & 7, ch = bid >> 3;
    const int c = ch * 64 + (t >> 2), part = t & 3;
    float r1 = 0, r2 = 0, r3 = 0, r4 = 0;
    for (int d = part * 128; d < part * 128 + 128; ++d){
      float v0 = rel[c + d];        r1 += v0; r2 += v0 * v0;
      float v1 = rel[1023 + c + d]; r3 += v1; r4 += v1 * v1;
    }
    #pragma unroll
    for (int off = 1; off < 4; off <<= 1){
      r1 += __shfl_xor(r1, off); r2 += __shfl_xor(r2, off);
      r3 += __shfl_xor(r3, off); r4 += __shfl_xor(r4, off);
    }
    double sq1 = 0, sq2 = 0, sk1 = 0, sk2 = 0;
    if (part == 0){
      float qa = 0, qb = 0, ka = 0, kb = 0;
      for (int b = 0; b < 8; ++b){
        float v = QS[(size_t)(b * 8 + g) * 512 + c]; qa += v; qb += v * v;
        float w = KS[(size_t)(b * 8 + g) * 512 + c]; ka += w; kb += w * w;
      }
      sq1 = (double)r1 * qa; sq2 = (double)r2 * qb;
      sk1 = (double)r3 * ka; sk2 = (double)r4 * kb;
    }
    sq1 = block_reduce_d(sq1);
    sq2 = block_reduce_d(sq2);
    sk1 = block_reduce_d(sk1);
    sk2 = block_reduce_d(sk2);
    if (t == 0){
      atomicAdd(&stats[g * 6 + 2], sq1);
      atomicAdd(&stats[g * 6 + 3], sq2);
      atomicAdd(&stats[g * 6 + 4], sk1);
      atomicAdd(&stats[g * 6 + 5], sk2);
    }
  } else if (bid < 1088){
    // ---- QKbf = bf16( q @ k^T ) + per-g sum/sumsq ----
    const int qb = bid - 64;
    const int nt = qb & 3, mt = (qb >> 2) & 3, bg = qb >> 4;
    const int b = bg >> 3, g = bg & 7;
    f32x4 acc[4][4];
    #pragma unroll
    for (int m = 0; m < 4; ++m)
      #pragma unroll
      for (int n = 0; n < 4; ++n) acc[m][n] = {0.f, 0.f, 0.f, 0.f};
    const short* q  = Ybf + (size_t)(b * 1536 + g * 192) * 1024;
    const short* kp = q + 65536;
    mfma_loop<4>(q + (size_t)mt * 128 * 128, 128, kp + (size_t)nt * 128 * 128, 128,
                 lds, lds + 8192, t, acc);
    const int l = t & 63, w = t >> 6, wr = (w >> 1) * 64, wc = (w & 1) * 64;
    short* out = QKbf + (size_t)bg * 262144 + (size_t)(mt * 128 + wr) * 512 + nt * 128 + wc;
    float s1 = 0.f, s2 = 0.f;
    #pragma unroll
    for (int m = 0; m < 4; ++m)
      #pragma unroll
      for (int n = 0; n < 4; ++n)
        #pragma unroll
        for (int j = 0; j < 4; ++j){
          float vl = acc[m][n][j];
          s1 += vl; s2 += vl * vl;
          out[(size_t)(m * 16 + (l >> 4) * 4 + j) * 512 + n * 16 + (l & 15)] = f2bf(vl);
        }
    float S1 = block_reduce_f<false>(s1);
    float S2 = block_reduce_f<false>(s2);
    if (t == 0){
      atomicAdd(&stats[g * 6 + 0], (double)S1);
      atomicAdd(&stats[g * 6 + 1], (double)S2);
    }
  } else {
    // ---- V transpose: per bg, Ybf rows [+128,+192) viewed [512][128] -> Vt [bg][128][512] ----
    const int vb = bid - 1088;
    const int jt = vb & 1, iit = (vb >> 1) & 7, bg = vb >> 4;
    const int b = bg >> 3, g = bg & 7;
    short (*s)[72] = (short(*)[72])lds;   // 64x72 shorts = 9216 B, fits in the 16 KB pool
    const short* V = Ybf + (size_t)(b * 1536 + g * 192 + 128) * 1024;
    const int rl = t >> 2, cs = (t & 3) * 16;
    const short* src = V + (size_t)(iit * 64 + rl) * 128 + jt * 64 + cs;
    *(bf16x8*)&s[rl][cs]     = *(const bf16x8*)src;
    *(bf16x8*)&s[rl][cs + 8] = *(const bf16x8*)(src + 8);
    __syncthreads();
    bf16x8 a0, a1;
    #pragma unroll
    for (int e = 0; e < 8; ++e){ a0[e] = s[cs + e][rl]; a1[e] = s[cs + 8 + e][rl]; }
    short* dst = Vt + ((size_t)bg * 128 + jt * 64 + rl) * 512 + iit * 64 + cs;
    *(bf16x8*)dst = a0;
    *(bf16x8*)(dst + 8) = a1;
  }
}

// ---------------- fused BN + sum + softmax + sve; wave per row, no syncs ----------------
// No max subtraction: s is a sum of 3 BN-standardized fields (|s| ~ 20), exp fp32-safe —
// validated in R7/R9/R10 (absmax bit-identical to max-subtracted version).
__global__ __launch_bounds__(256) void k_softmax(short* __restrict__ QKbf,
    const float* __restrict__ QS, const float* __restrict__ KS,
    const float* __restrict__ rel, const double* __restrict__ stats,
    const float* __restrict__ bnw, const float* __restrict__ bnb,
    const float* __restrict__ fqr, const float* __restrict__ fkr,
    const float* __restrict__ fsve, float* __restrict__ SVE, float* __restrict__ S12){
  const int row = blockIdx.x * 4 + (threadIdx.x >> 6);   // (b*8+g)*512 + c
  const int l = threadIdx.x & 63;
  const int bg = row >> 9, c = row & 511, g = bg & 7;
  // inline BN coefficients (uniform per block)
  const double M = 2097152.0; // 8*512*512
  double mu0  = stats[g*6+0] / M;
  double var0 = stats[g*6+1] / M - mu0*mu0;
  double A0d  = (double)bnw[g] / sqrt(var0 + 1e-5);
  double fq   = (double)fqr[0];
  double mu1  = fq * stats[g*6+2] / M;
  double var1 = fq*fq * stats[g*6+3] / M - mu1*mu1;
  double A1d  = (double)bnw[8+g] / sqrt(var1 + 1e-5);
  double fk   = (double)fkr[0];
  double mu2  = fk * stats[g*6+4] / M;
  double var2 = fk*fk * stats[g*6+5] / M - mu2*mu2;
  double A2d  = (double)bnw[16+g] / sqrt(var2 + 1e-5);
  double Cgd  = ((double)bnb[g] - mu0*A0d) + ((double)bnb[8+g] - mu1*A1d)
              + ((double)bnb[16+g] - mu2*A2d);
  const float A0 = (float)A0d, B2 = (float)(A2d * fk), Cg = (float)Cgd;
  const float B1q = (float)(A1d * fq) * QS[row];

  short* __restrict__ qkrow = QKbf + (size_t)row * 512;
  const float* __restrict__ ksrow = KS + (size_t)bg * 512;
  const int j0 = l * 8;
  bf16x8 qk8 = *(const bf16x8*)(qkrow + j0);
  float4 ks0 = *(const float4*)(ksrow + j0);
  float4 ks1 = *(const float4*)(ksrow + j0 + 4);
  float ks[8] = {ks0.x, ks0.y, ks0.z, ks0.w, ks1.x, ks1.y, ks1.z, ks1.w};
  const float* relq = rel + 511 + c - j0;      // descending in e
  const float* relk = rel + 1534 + j0 - c;     // ascending in e
  float s[8];
  float sum = 0.f;
  #pragma unroll
  for (int e = 0; e < 8; ++e){
    float sc = A0 * bf2f(qk8[e]) + B1q * relq[-e] + B2 * ks[e] * relk[e] + Cg;
    s[e] = __expf(sc);
    sum += s[e];
  }
  #pragma unroll
  for (int off = 32; off; off >>= 1) sum += __shfl_xor(sum, off);
  const float inv = 1.0f / sum;
  const float* relv = rel + 2557 + c - j0;     // descending in e
  float sve = 0.f;
  bf16x8 p8;
  #pragma unroll
  for (int e = 0; e < 8; ++e){
    float p = s[e] * inv;
    p8[e] = f2bf(p);
    sve += p * relv[-e];
  }
  *(bf16x8*)(qkrow + j0) = p8;
  #pragma unroll
  for (int off = 32; off; off >>= 1) sve += __shfl_xor(sve, off);
  if (l == 0){
    float e = fsve[0] * sve;
    SVE[row] = e;
    const int b = bg >> 3;
    atomicAdd(&S12[b * 512 + c],        128.f * e);
    atomicAdd(&S12[4096 + b * 512 + c], 128.f * e * e);
  }
}

// ---------------- K5: SV2[bg][c][j] = bf16(f_sv * sum_i P[c,i] Vt[j,i]) + LN stat partials ---
__global__ __launch_bounds__(256) void k_sv(const short* __restrict__ Pbf,
                                            const short* __restrict__ Vt,
                                            const float* __restrict__ fsv,
                                            short* __restrict__ SV2,
                                            float* __restrict__ S12){
  const int bg = blockIdx.z, mt = blockIdx.x;   // M=512 (c): 4 tiles; N=128 (j): 1 tile
  __shared__ char lds[16384];
  __shared__ float s1buf[128], s2buf[128];
  const int t = threadIdx.x;
  s1buf[t & 127] = 0.f; s2buf[t & 127] = 0.f;   // pre-loop sync happens inside mfma_loop
  f32x4 acc[4][4];
  #pragma unroll
  for (int m = 0; m < 4; ++m)
    #pragma unroll
    for (int n = 0; n < 4; ++n) acc[m][n] = {0.f, 0.f, 0.f, 0.f};
  const short* A = Pbf + (size_t)bg * 512 * 512 + (size_t)mt * 128 * 512;
  const short* B = Vt  + (size_t)bg * 128 * 512;
  mfma_loop<16>(A, 512, B, 512, lds, lds + 8192, t, acc);
  const int l = t & 63, w = t >> 6, wr = (w >> 1) * 64, wc = (w & 1) * 64;
  const float fv = fsv[0];
  short* out = SV2 + (size_t)bg * 512 * 128 + (size_t)(mt * 128 + wr) * 128 + wc;
  #pragma unroll
  for (int m = 0; m < 4; ++m)
    #pragma unroll
    for (int jr = 0; jr < 4; ++jr){
      float p1 = 0.f, p2 = 0.f;
      #pragma unroll
      for (int n = 0; n < 4; ++n){
        float vl = acc[m][n][jr] * fv;
        p1 += vl; p2 += vl * vl;
        out[(size_t)(m * 16 + (l >> 4) * 4 + jr) * 128 + n * 16 + (l & 15)] = f2bf(vl);
      }
      #pragma unroll
      for (int off = 1; off < 16; off <<= 1){
        p1 += __shfl_xor(p1, off);
        p2 += __shfl_xor(p2, off);
      }
      if ((l & 15) == 0){
        int rloc = wr + m * 16 + (l >> 4) * 4 + jr;
        atomicAdd(&s1buf[rloc], p1);
        atomicAdd(&s2buf[rloc], p2);
      }
    }
  __syncthreads();
  if (t < 128){
    const int b = bg >> 3;
    const int ci = b * 512 + mt * 128 + t;
    atomicAdd(&S12[ci],        s1buf[t]);
    atomicAdd(&S12[4096 + ci], s2buf[t]);
  }
}

// ---------------- K6: normalize + fold + residual; mean/rstd from S12 inline ----------------
__global__ __launch_bounds__(256) void k_out(const short* __restrict__ SV2,
    const float* __restrict__ SVE, const float* __restrict__ S12,
    const float* __restrict__ X, const float* __restrict__ gam, float* __restrict__ OUT){
  const int c2t = blockIdx.x, g = blockIdx.y, b = blockIdx.z;
  const int bg = b * 8 + g;
  const int c20 = c2t * 64;
  __shared__ float s[64][129];
  const int t = threadIdx.x;
  {
    const int col8 = (t & 15) * 8;
    #pragma unroll
    for (int r0 = 0; r0 < 64; r0 += 16){
      int row = r0 + (t >> 4);
      bf16x8 v = *(const bf16x8*)(SV2 + (size_t)bg * 65536 + (size_t)(c20 + row) * 128 + col8);
      #pragma unroll
      for (int e = 0; e < 8; ++e) s[row][col8 + e] = bf2f(v[e]);
    }
  }
  __syncthreads();
  const int lane = t & 63, w = t >> 6;
  const int c2 = c20 + lane;
  const float sm1 = S12[b * 512 + c2];
  const float sm2 = S12[4096 + b * 512 + c2];
  const float mean = sm1 * (1.f / 2048.f);
  const float rs   = rsqrtf(sm2 * (1.f / 2048.f) - mean * mean + 1e-5f);
  const float e    = SVE[(size_t)bg * 512 + c2];
  const float gm   = gam[0];
  for (int j = w; j < 128; j += 4){
    float v = s[lane][j];
    float o = (v + e - 2.f * mean) * rs;
    int chan = g * 64 + (j >> 1);
    size_t oi = ((size_t)b * 512 + chan) * 1024 + ((j & 1) << 9) + c2;
    OUT[oi] = gm * o + X[oi];
  }
}

extern "C" void kernel_launch(void* const* d_in, const int* in_sizes, int n_in,
                              void* d_out, int out_size, void* d_ws, size_t ws_size,
                              hipStream_t stream){
  const float* X    = (const float*)d_in[0];
  const float* W    = (const float*)d_in[1];
  const float* REL  = (const float*)d_in[2];
  const float* BNW  = (const float*)d_in[3];
  const float* BNB  = (const float*)d_in[4];
  const float* FQR  = (const float*)d_in[5];
  const float* FKR  = (const float*)d_in[6];
  const float* FSV  = (const float*)d_in[7];
  const float* FSVE = (const float*)d_in[8];
  const float* GAM  = (const float*)d_in[9];
  float* OUT = (float*)d_out;

  char* ws = (char*)d_ws;
  short*  Ybf   = (short*) (ws + 0ull);          // 25,165,824 B  (8,1536,1024) bf16
  short*  QKbf  = (short*) (ws + 25165824ull);   // 33,554,432 B  (64,512,512) bf16 (qk then P)
  short*  SV2   = (short*) (ws + 58720256ull);   //  8,388,608 B  (64,512,128) bf16 [bg][c][j]
  short*  Wbf   = (short*) (ws + 75497472ull);   //  1,572,864 B
  short*  Xt    = (short*) (ws + 77070336ull);   //  8,388,608 B  (8,1024,512) bf16
  short*  Vt    = (short*) (ws + 85458944ull);   //  8,388,608 B  (64,128,512) bf16
  float*  QS    = (float*) (ws + 93847552ull);   //    131,072 B
  float*  KS    = (float*) (ws + 93978624ull);   //    131,072 B
  float*  SVE   = (float*) (ws + 94109696ull);   //    131,072 B
  double* STATS = (double*)(ws + 94240768ull);   //        384 B (48 doubles)
  float*  S12   = (float*) (ws + 94249472ull);   //     32,768 B (2 x 8*512 fp32)

  k_prep   <<<1792,            256, 0, stream>>>(X, Xt, W, Wbf, STATS, S12);
  k_gemm1  <<<dim3(8, 12, 8),  256, 0, stream>>>(Wbf, Xt, Ybf);
  k_ln     <<<3072,            256, 0, stream>>>(Ybf, QS, KS);
  k_mid    <<<2112,            256, 0, stream>>>(Ybf, QKbf, Vt, QS, KS, REL, STATS);
  k_softmax<<<8192,            256, 0, stream>>>(QKbf, QS, KS, REL, STATS,
                                                 BNW, BNB, FQR, FKR, FSVE, SVE, S12);
  k_sv     <<<dim3(4, 1, 64),  256, 0, stream>>>(QKbf, Vt, FSV, SV2, S12);
  k_out    <<<dim3(8, 8, 8),   256, 0, stream>>>(SV2, SVE, S12, X, GAM, OUT);
}

// Round 12
// 113.983 us; speedup vs baseline: 1.3269x; 1.0382x over previous
//
#include <hip/hip_runtime.h>
#include <math.h>

#define DEV_INLINE __device__ __forceinline__

typedef short bf16x8 __attribute__((ext_vector_type(8)));
typedef float f32x4  __attribute__((ext_vector_type(4)));

// Problem constants: N=8, C=512, HW=1024, OC=3C=1536, G=8, gp=128

DEV_INLINE float bf2f(short h){
  union { unsigned u; float f; } x; x.u = ((unsigned)(unsigned short)h) << 16; return x.f;
}
DEV_INLINE short f2bf(float f){
  union { float f; unsigned u; } x; x.f = f;
  unsigned r = x.u + 0x7FFF + ((x.u >> 16) & 1);
  return (short)(r >> 16);
}

// ---------------- block reduction helpers (blockDim == 256) ----------------
template<bool MAXOP>
DEV_INLINE float block_reduce_f(float v){
  __shared__ float tmp[4];
  const int lane = threadIdx.x & 63, w = threadIdx.x >> 6;
  #pragma unroll
  for (int off = 32; off; off >>= 1){
    float o = __shfl_down(v, off);
    v = MAXOP ? fmaxf(v, o) : (v + o);
  }
  __syncthreads();
  if (lane == 0) tmp[w] = v;
  __syncthreads();
  return MAXOP ? fmaxf(fmaxf(tmp[0], tmp[1]), fmaxf(tmp[2], tmp[3]))
               : (tmp[0] + tmp[1] + tmp[2] + tmp[3]);
}

DEV_INLINE double block_reduce_d(double v){
  __shared__ double tmp[4];
  const int lane = threadIdx.x & 63, w = threadIdx.x >> 6;
  #pragma unroll
  for (int off = 32; off; off >>= 1) v += __shfl_down(v, off);
  __syncthreads();
  if (lane == 0) tmp[w] = v;
  __syncthreads();
  return tmp[0] + tmp[1] + tmp[2] + tmp[3];
}

// ---------------- MFMA tile machinery — BK=64 (halves barrier drains vs BK=32;
// occupancy unchanged: VGPR-capped ~5 blocks/CU == 32KB-LDS cap; m132's BK=128
// regression was the 64KB/2-block cliff). Tile: 128 rows x 64 bf16 (128B rows),
// XOR-swizzle byte ^= (row&7)<<4 -> 8 rows spread over all 8 16B slots. ----------------

DEV_INLINE void stage64(const short* __restrict__ g, int ldk, char* lds_region, int t){
  #pragma unroll
  for (int r = 0; r < 4; ++r){
    int o   = t * 16 + r * 4096;           // physical LDS byte of this 16B chunk
    int row = o >> 7, wb = o & 127;
    int swb = wb ^ ((row & 7) << 4);
    const short* src = g + (size_t)row * ldk + (swb >> 1);
    char* dst = lds_region + ((t >> 6) << 10) + (r << 12); // wave-uniform + lane*16
    __builtin_amdgcn_global_load_lds((const __attribute__((address_space(1))) void*)src,
                                     (__attribute__((address_space(3))) void*)dst, 16, 0, 0);
  }
}

DEV_INLINE bf16x8 read_frag64(const char* base, int row, int kgrp){
  int off = row * 128 + ((kgrp ^ (row & 7)) << 4);
  return *(const bf16x8*)(base + off);
}

// A: row-major [M][K] bf16, B^T: row-major [N][K] bf16 (both K-contiguous).
// Block: 256 thr = 4 waves (2x2 of 64x64), tile 128x128, BK=64 consumed in two
// K=32 halves (register pressure identical to BK=32).
template<int KT64>
DEV_INLINE void mfma_loop64(const short* __restrict__ A, int ldA,
                            const short* __restrict__ B, int ldB,
                            char* ldsA, char* ldsB, int t, f32x4 acc[4][4]){
  const int l = t & 63, w = t >> 6;
  const int wr = (w >> 1) * 64, wc = (w & 1) * 64;
  for (int kt = 0; kt < KT64; ++kt){
    stage64(A + kt * 64, ldA, ldsA, t);
    stage64(B + kt * 64, ldB, ldsB, t);
    __syncthreads();
    #pragma unroll
    for (int h = 0; h < 2; ++h){
      bf16x8 af[4], bfr[4];
      #pragma unroll
      for (int m = 0; m < 4; ++m) af[m]  = read_frag64(ldsA, wr + m * 16 + (l & 15), (l >> 4) + h * 4);
      #pragma unroll
      for (int n = 0; n < 4; ++n) bfr[n] = read_frag64(ldsB, wc + n * 16 + (l & 15), (l >> 4) + h * 4);
      #pragma unroll
      for (int m = 0; m < 4; ++m)
        #pragma unroll
        for (int n = 0; n < 4; ++n)
          acc[m][n] = __builtin_amdgcn_mfma_f32_16x16x32_bf16(af[m], bfr[n], acc[m][n], 0, 0, 0);
    }
    __syncthreads();
  }
}

// ---------------- K0: combined prep — Xt transpose-convert + W convert + zeroing ------
__global__ __launch_bounds__(256) void k_prep(const float* __restrict__ X, short* __restrict__ Xt,
                                              const float* __restrict__ W, short* __restrict__ Wbf,
                                              double* __restrict__ stats, float* __restrict__ S12){
  __shared__ short s[64][72];
  const int bid = blockIdx.x;
  const int t = threadIdx.x;
  if (bid < 1024){
    const int it = bid & 15, kt = (bid >> 4) & 7, b = bid >> 7;
    const int rl = t >> 2, cs = (t & 3) * 16;
    const float* src = X + ((size_t)b * 512 + kt * 64 + rl) * 1024 + it * 64 + cs;
    #pragma unroll
    for (int e = 0; e < 16; e += 4){
      float4 v = *(const float4*)(src + e);
      s[rl][cs + e + 0] = f2bf(v.x); s[rl][cs + e + 1] = f2bf(v.y);
      s[rl][cs + e + 2] = f2bf(v.z); s[rl][cs + e + 3] = f2bf(v.w);
    }
    __syncthreads();
    bf16x8 a0, a1;
    #pragma unroll
    for (int e = 0; e < 8; ++e){ a0[e] = s[cs + e][rl]; a1[e] = s[cs + 8 + e][rl]; }
    short* dst = Xt + ((size_t)b * 1024 + it * 64 + rl) * 512 + kt * 64 + cs;
    *(bf16x8*)dst = a0;
    *(bf16x8*)(dst + 8) = a1;
  } else {
    const int gi = (bid - 1024) * 256 + t;
    if (gi < 48) stats[gi] = 0.0;
    if (gi < 8192) S12[gi] = 0.f;
    const int i = gi * 4;
    float4 v = *(const float4*)(W + i);
    short4 o; o.x = f2bf(v.x); o.y = f2bf(v.y); o.z = f2bf(v.z); o.w = f2bf(v.w);
    *(short4*)(Wbf + i) = o;
  }
}

// ---------------- K1: Ybf = bf16( W @ X ), pre-LN ----------------
__global__ __launch_bounds__(256) void k_gemm1(const short* __restrict__ Wbf,
                                               const short* __restrict__ Xt,
                                               short* __restrict__ Ybf){
  const int b = blockIdx.z, mt = blockIdx.y, nt = blockIdx.x;
  __shared__ char lds[32768];
  const int t = threadIdx.x;
  f32x4 acc[4][4];
  #pragma unroll
  for (int m = 0; m < 4; ++m)
    #pragma unroll
    for (int n = 0; n < 4; ++n) acc[m][n] = {0.f, 0.f, 0.f, 0.f};
  const short* A = Wbf + (size_t)mt * 128 * 512;
  const short* B = Xt + (size_t)b * 1024 * 512 + (size_t)nt * 128 * 512;
  mfma_loop64<8>(A, 512, B, 512, lds, lds + 16384, t, acc);
  const int l = t & 63, w = t >> 6, wr = (w >> 1) * 64, wc = (w & 1) * 64;
  short* out = Ybf + (size_t)b * 1536 * 1024 + (size_t)(mt * 128 + wr) * 1024 + nt * 128 + wc;
  #pragma unroll
  for (int m = 0; m < 4; ++m)
    #pragma unroll
    for (int n = 0; n < 4; ++n)
      #pragma unroll
      for (int j = 0; j < 4; ++j)
        out[(size_t)(m * 16 + (l >> 4) * 4 + j) * 1024 + n * 16 + (l & 15)] = f2bf(acc[m][n][j]);
}

// ---------------- K1b: wave-per-row LN of Ybf (1024 cols) + q/k chunk sums ----------------
__global__ __launch_bounds__(256) void k_ln(short* __restrict__ Ybf,
                                            float* __restrict__ QS, float* __restrict__ KS){
  const int row = blockIdx.x * 4 + (threadIdx.x >> 6);   // b*1536 + o
  const int l = threadIdx.x & 63;
  short* p = Ybf + (size_t)row * 1024 + l * 16;
  bf16x8 v0 = *(const bf16x8*)p;
  bf16x8 v1 = *(const bf16x8*)(p + 8);
  float f[16];
  #pragma unroll
  for (int e = 0; e < 8; ++e){ f[e] = bf2f(v0[e]); f[8 + e] = bf2f(v1[e]); }
  float s1 = 0.f, s2 = 0.f;
  #pragma unroll
  for (int e = 0; e < 16; ++e){ s1 += f[e]; s2 += f[e] * f[e]; }
  #pragma unroll
  for (int off = 32; off; off >>= 1){ s1 += __shfl_xor(s1, off); s2 += __shfl_xor(s2, off); }
  float mean = s1 * (1.f / 1024.f);
  float r = rsqrtf(s2 * (1.f / 1024.f) - mean * mean + 1e-5f);
  float cs = 0.f;
  #pragma unroll
  for (int e = 0; e < 16; ++e){ f[e] = (f[e] - mean) * r; cs += f[e]; }
  bf16x8 o0, o1;
  #pragma unroll
  for (int e = 0; e < 8; ++e){ o0[e] = f2bf(f[e]); o1[e] = f2bf(f[8 + e]); }
  *(bf16x8*)p = o0;
  *(bf16x8*)(p + 8) = o1;
  // chunk sums: chunk = l>>3 (128 elems = 8 lanes x 16)
  cs += __shfl_xor(cs, 1); cs += __shfl_xor(cs, 2); cs += __shfl_xor(cs, 4);
  const int o = row % 1536, ol = o % 192;
  if ((l & 7) == 0 && ol < 128){
    const int b = row / 1536, g = o / 192;
    const int c = (ol & 63) * 8 + (l >> 3);
    const int idx = (b * 8 + g) * 512 + c;
    if (ol < 64) QS[idx] = cs; else KS[idx] = cs;
  }
}

// ---------------- K2: merged mid-stage — qrkr stats | qk GEMM | V transpose ----------------
// blockIdx.x: [0,64) qrkr | [64,1088) qk | [1088,2112) vt
__global__ __launch_bounds__(256) void k_mid(const short* __restrict__ Ybf,
                                             short* __restrict__ QKbf,
                                             short* __restrict__ Vt,
                                             const float* __restrict__ QS,
                                             const float* __restrict__ KS,
                                             const float* __restrict__ rel,
                                             double* __restrict__ stats){
  __shared__ char lds[32768];
  const int bid = blockIdx.x;
  const int t = threadIdx.x;

  if (bid < 64){
    // ---- qr/kr closed-form stats (g x 8 c-chunks) ----
    const int g = bid & 7, ch = bid >> 3;
    const int c = ch * 64 + (t >> 2), part = t & 3;
    float r1 = 0, r2 = 0, r3 = 0, r4 = 0;
    for (int d = part * 128; d < part * 128 + 128; ++d){
      float v0 = rel[c + d];        r1 += v0; r2 += v0 * v0;
      float v1 = rel[1023 + c + d]; r3 += v1; r4 += v1 * v1;
    }
    #pragma unroll
    for (int off = 1; off < 4; off <<= 1){
      r1 += __shfl_xor(r1, off); r2 += __shfl_xor(r2, off);
      r3 += __shfl_xor(r3, off); r4 += __shfl_xor(r4, off);
    }
    double sq1 = 0, sq2 = 0, sk1 = 0, sk2 = 0;
    if (part == 0){
      float qa = 0, qb = 0, ka = 0, kb = 0;
      for (int b = 0; b < 8; ++b){
        float v = QS[(size_t)(b * 8 + g) * 512 + c]; qa += v; qb += v * v;
        float w = KS[(size_t)(b * 8 + g) * 512 + c]; ka += w; kb += w * w;
      }
      sq1 = (double)r1 * qa; sq2 = (double)r2 * qb;
      sk1 = (double)r3 * ka; sk2 = (double)r4 * kb;
    }
    sq1 = block_reduce_d(sq1);
    sq2 = block_reduce_d(sq2);
    sk1 = block_reduce_d(sk1);
    sk2 = block_reduce_d(sk2);
    if (t == 0){
      atomicAdd(&stats[g * 6 + 2], sq1);
      atomicAdd(&stats[g * 6 + 3], sq2);
      atomicAdd(&stats[g * 6 + 4], sk1);
      atomicAdd(&stats[g * 6 + 5], sk2);
    }
  } else if (bid < 1088){
    // ---- QKbf = bf16( q @ k^T ) + per-g sum/sumsq ----
    const int qb = bid - 64;
    const int nt = qb & 3, mt = (qb >> 2) & 3, bg = qb >> 4;
    const int b = bg >> 3, g = bg & 7;
    f32x4 acc[4][4];
    #pragma unroll
    for (int m = 0; m < 4; ++m)
      #pragma unroll
      for (int n = 0; n < 4; ++n) acc[m][n] = {0.f, 0.f, 0.f, 0.f};
    const short* q  = Ybf + (size_t)(b * 1536 + g * 192) * 1024;
    const short* kp = q + 65536;
    mfma_loop64<2>(q + (size_t)mt * 128 * 128, 128, kp + (size_t)nt * 128 * 128, 128,
                   lds, lds + 16384, t, acc);
    const int l = t & 63, w = t >> 6, wr = (w >> 1) * 64, wc = (w & 1) * 64;
    short* out = QKbf + (size_t)bg * 262144 + (size_t)(mt * 128 + wr) * 512 + nt * 128 + wc;
    float s1 = 0.f, s2 = 0.f;
    #pragma unroll
    for (int m = 0; m < 4; ++m)
      #pragma unroll
      for (int n = 0; n < 4; ++n)
        #pragma unroll
        for (int j = 0; j < 4; ++j){
          float vl = acc[m][n][j];
          s1 += vl; s2 += vl * vl;
          out[(size_t)(m * 16 + (l >> 4) * 4 + j) * 512 + n * 16 + (l & 15)] = f2bf(vl);
        }
    float S1 = block_reduce_f<false>(s1);
    float S2 = block_reduce_f<false>(s2);
    if (t == 0){
      atomicAdd(&stats[g * 6 + 0], (double)S1);
      atomicAdd(&stats[g * 6 + 1], (double)S2);
    }
  } else {
    // ---- V transpose: per bg, Ybf rows [+128,+192) viewed [512][128] -> Vt [bg][128][512] ----
    const int vb = bid - 1088;
    const int jt = vb & 1, iit = (vb >> 1) & 7, bg = vb >> 4;
    const int b = bg >> 3, g = bg & 7;
    short (*s)[72] = (short(*)[72])lds;   // 64x72 shorts = 9216 B
    const short* V = Ybf + (size_t)(b * 1536 + g * 192 + 128) * 1024;
    const int rl = t >> 2, cs = (t & 3) * 16;
    const short* src = V + (size_t)(iit * 64 + rl) * 128 + jt * 64 + cs;
    *(bf16x8*)&s[rl][cs]     = *(const bf16x8*)src;
    *(bf16x8*)&s[rl][cs + 8] = *(const bf16x8*)(src + 8);
    __syncthreads();
    bf16x8 a0, a1;
    #pragma unroll
    for (int e = 0; e < 8; ++e){ a0[e] = s[cs + e][rl]; a1[e] = s[cs + 8 + e][rl]; }
    short* dst = Vt + ((size_t)bg * 128 + jt * 64 + rl) * 512 + iit * 64 + cs;
    *(bf16x8*)dst = a0;
    *(bf16x8*)(dst + 8) = a1;
  }
}

// ---------------- fused BN + sum + softmax + sve; wave per row, no syncs ----------------
// No max subtraction: s is a sum of 3 BN-standardized fields (|s| ~ 20), exp fp32-safe —
// validated in R7/R9/R10 (absmax bit-identical to max-subtracted version).
__global__ __launch_bounds__(256) void k_softmax(short* __restrict__ QKbf,
    const float* __restrict__ QS, const float* __restrict__ KS,
    const float* __restrict__ rel, const double* __restrict__ stats,
    const float* __restrict__ bnw, const float* __restrict__ bnb,
    const float* __restrict__ fqr, const float* __restrict__ fkr,
    const float* __restrict__ fsve, float* __restrict__ SVE, float* __restrict__ S12){
  const int row = blockIdx.x * 4 + (threadIdx.x >> 6);   // (b*8+g)*512 + c
  const int l = threadIdx.x & 63;
  const int bg = row >> 9, c = row & 511, g = bg & 7;
  // inline BN coefficients (uniform per block)
  const double M = 2097152.0; // 8*512*512
  double mu0  = stats[g*6+0] / M;
  double var0 = stats[g*6+1] / M - mu0*mu0;
  double A0d  = (double)bnw[g] / sqrt(var0 + 1e-5);
  double fq   = (double)fqr[0];
  double mu1  = fq * stats[g*6+2] / M;
  double var1 = fq*fq * stats[g*6+3] / M - mu1*mu1;
  double A1d  = (double)bnw[8+g] / sqrt(var1 + 1e-5);
  double fk   = (double)fkr[0];
  double mu2  = fk * stats[g*6+4] / M;
  double var2 = fk*fk * stats[g*6+5] / M - mu2*mu2;
  double A2d  = (double)bnw[16+g] / sqrt(var2 + 1e-5);
  double Cgd  = ((double)bnb[g] - mu0*A0d) + ((double)bnb[8+g] - mu1*A1d)
              + ((double)bnb[16+g] - mu2*A2d);
  const float A0 = (float)A0d, B2 = (float)(A2d * fk), Cg = (float)Cgd;
  const float B1q = (float)(A1d * fq) * QS[row];

  short* __restrict__ qkrow = QKbf + (size_t)row * 512;
  const float* __restrict__ ksrow = KS + (size_t)bg * 512;
  const int j0 = l * 8;
  bf16x8 qk8 = *(const bf16x8*)(qkrow + j0);
  float4 ks0 = *(const float4*)(ksrow + j0);
  float4 ks1 = *(const float4*)(ksrow + j0 + 4);
  float ks[8] = {ks0.x, ks0.y, ks0.z, ks0.w, ks1.x, ks1.y, ks1.z, ks1.w};
  const float* relq = rel + 511 + c - j0;      // descending in e
  const float* relk = rel + 1534 + j0 - c;     // ascending in e
  float s[8];
  float sum = 0.f;
  #pragma unroll
  for (int e = 0; e < 8; ++e){
    float sc = A0 * bf2f(qk8[e]) + B1q * relq[-e] + B2 * ks[e] * relk[e] + Cg;
    s[e] = __expf(sc);
    sum += s[e];
  }
  #pragma unroll
  for (int off = 32; off; off >>= 1) sum += __shfl_xor(sum, off);
  const float inv = 1.0f / sum;
  const float* relv = rel + 2557 + c - j0;     // descending in e
  float sve = 0.f;
  bf16x8 p8;
  #pragma unroll
  for (int e = 0; e < 8; ++e){
    float p = s[e] * inv;
    p8[e] = f2bf(p);
    sve += p * relv[-e];
  }
  *(bf16x8*)(qkrow + j0) = p8;
  #pragma unroll
  for (int off = 32; off; off >>= 1) sve += __shfl_xor(sve, off);
  if (l == 0){
    float e = fsve[0] * sve;
    SVE[row] = e;
    const int b = bg >> 3;
    atomicAdd(&S12[b * 512 + c],        128.f * e);
    atomicAdd(&S12[4096 + b * 512 + c], 128.f * e * e);
  }
}

// ---------------- K5: SV2[bg][c][j] = bf16(f_sv * sum_i P[c,i] Vt[j,i]) + LN stat partials ---
__global__ __launch_bounds__(256) void k_sv(const short* __restrict__ Pbf,
                                            const short* __restrict__ Vt,
                                            const float* __restrict__ fsv,
                                            short* __restrict__ SV2,
                                            float* __restrict__ S12){
  const int bg = blockIdx.z, mt = blockIdx.x;   // M=512 (c): 4 tiles; N=128 (j): 1 tile
  __shared__ char lds[32768];
  __shared__ float s1buf[128], s2buf[128];
  const int t = threadIdx.x;
  s1buf[t & 127] = 0.f; s2buf[t & 127] = 0.f;   // pre-loop sync happens inside mfma_loop64
  f32x4 acc[4][4];
  #pragma unroll
  for (int m = 0; m < 4; ++m)
    #pragma unroll
    for (int n = 0; n < 4; ++n) acc[m][n] = {0.f, 0.f, 0.f, 0.f};
  const short* A = Pbf + (size_t)bg * 262144 + (size_t)mt * 128 * 512;
  const short* B = Vt  + (size_t)bg * 65536;
  mfma_loop64<8>(A, 512, B, 512, lds, lds + 16384, t, acc);
  const int l = t & 63, w = t >> 6, wr = (w >> 1) * 64, wc = (w & 1) * 64;
  const float fv = fsv[0];
  short* out = SV2 + (size_t)bg * 65536 + (size_t)(mt * 128 + wr) * 128 + wc;
  #pragma unroll
  for (int m = 0; m < 4; ++m)
    #pragma unroll
    for (int jr = 0; jr < 4; ++jr){
      float p1 = 0.f, p2 = 0.f;
      #pragma unroll
      for (int n = 0; n < 4; ++n){
        float vl = acc[m][n][jr] * fv;
        p1 += vl; p2 += vl * vl;
        out[(size_t)(m * 16 + (l >> 4) * 4 + jr) * 128 + n * 16 + (l & 15)] = f2bf(vl);
      }
      #pragma unroll
      for (int off = 1; off < 16; off <<= 1){
        p1 += __shfl_xor(p1, off);
        p2 += __shfl_xor(p2, off);
      }
      if ((l & 15) == 0){
        int rloc = wr + m * 16 + (l >> 4) * 4 + jr;
        atomicAdd(&s1buf[rloc], p1);
        atomicAdd(&s2buf[rloc], p2);
      }
    }
  __syncthreads();
  if (t < 128){
    const int b = bg >> 3;
    const int ci = b * 512 + mt * 128 + t;
    atomicAdd(&S12[ci],        s1buf[t]);
    atomicAdd(&S12[4096 + ci], s2buf[t]);
  }
}

// ---------------- K6: normalize + fold + residual; mean/rstd from S12 inline ----------------
__global__ __launch_bounds__(256) void k_out(const short* __restrict__ SV2,
    const float* __restrict__ SVE, const float* __restrict__ S12,
    const float* __restrict__ X, const float* __restrict__ gam, float* __restrict__ OUT){
  const int c2t = blockIdx.x, g = blockIdx.y, b = blockIdx.z;
  const int bg = b * 8 + g;
  const int c20 = c2t * 64;
  __shared__ float s[64][129];
  const int t = threadIdx.x;
  {
    const int col8 = (t & 15) * 8;
    #pragma unroll
    for (int r0 = 0; r0 < 64; r0 += 16){
      int row = r0 + (t >> 4);
      bf16x8 v = *(const bf16x8*)(SV2 + (size_t)bg * 65536 + (size_t)(c20 + row) * 128 + col8);
      #pragma unroll
      for (int e = 0; e < 8; ++e) s[row][col8 + e] = bf2f(v[e]);
    }
  }
  __syncthreads();
  const int lane = t & 63, w = t >> 6;
  const int c2 = c20 + lane;
  const float sm1 = S12[b * 512 + c2];
  const float sm2 = S12[4096 + b * 512 + c2];
  const float mean = sm1 * (1.f / 2048.f);
  const float rs   = rsqrtf(sm2 * (1.f / 2048.f) - mean * mean + 1e-5f);
  const float e    = SVE[(size_t)bg * 512 + c2];
  const float gm   = gam[0];
  for (int j = w; j < 128; j += 4){
    float v = s[lane][j];
    float o = (v + e - 2.f * mean) * rs;
    int chan = g * 64 + (j >> 1);
    size_t oi = ((size_t)b * 512 + chan) * 1024 + ((j & 1) << 9) + c2;
    OUT[oi] = gm * o + X[oi];
  }
}

extern "C" void kernel_launch(void* const* d_in, const int* in_sizes, int n_in,
                              void* d_out, int out_size, void* d_ws, size_t ws_size,
                              hipStream_t stream){
  const float* X    = (const float*)d_in[0];
  const float* W    = (const float*)d_in[1];
  const float* REL  = (const float*)d_in[2];
  const float* BNW  = (const float*)d_in[3];
  const float* BNB  = (const float*)d_in[4];
  const float* FQR  = (const float*)d_in[5];
  const float* FKR  = (const float*)d_in[6];
  const float* FSV  = (const float*)d_in[7];
  const float* FSVE = (const float*)d_in[8];
  const float* GAM  = (const float*)d_in[9];
  float* OUT = (float*)d_out;

  char* ws = (char*)d_ws;
  short*  Ybf   = (short*) (ws + 0ull);          // 25,165,824 B  (8,1536,1024) bf16
  short*  QKbf  = (short*) (ws + 25165824ull);   // 33,554,432 B  (64,512,512) bf16 (qk then P)
  short*  SV2   = (short*) (ws + 58720256ull);   //  8,388,608 B  (64,512,128) bf16 [bg][c][j]
  short*  Wbf   = (short*) (ws + 75497472ull);   //  1,572,864 B
  short*  Xt    = (short*) (ws + 77070336ull);   //  8,388,608 B  (8,1024,512) bf16
  short*  Vt    = (short*) (ws + 85458944ull);   //  8,388,608 B  (64,128,512) bf16
  float*  QS    = (float*) (ws + 93847552ull);   //    131,072 B
  float*  KS    = (float*) (ws + 93978624ull);   //    131,072 B
  float*  SVE   = (float*) (ws + 94109696ull);   //    131,072 B
  double* STATS = (double*)(ws + 94240768ull);   //        384 B (48 doubles)
  float*  S12   = (float*) (ws + 94249472ull);   //     32,768 B (2 x 8*512 fp32)

  k_prep   <<<1792,            256, 0, stream>>>(X, Xt, W, Wbf, STATS, S12);
  k_gemm1  <<<dim3(8, 12, 8),  256, 0, stream>>>(Wbf, Xt, Ybf);
  k_ln     <<<3072,            256, 0, stream>>>(Ybf, QS, KS);
  k_mid    <<<2112,            256, 0, stream>>>(Ybf, QKbf, Vt, QS, KS, REL, STATS);
  k_softmax<<<8192,            256, 0, stream>>>(QKbf, QS, KS, REL, STATS,
                                                 BNW, BNB, FQR, FKR, FSVE, SVE, S12);
  k_sv     <<<dim3(4, 1, 64),  256, 0, stream>>>(QKbf, Vt, FSV, SV2, S12);
  k_out    <<<dim3(8, 8, 8),   256, 0, stream>>>(SV2, SVE, S12, X, GAM, OUT);
}